// Round 15
// baseline (146.264 us; speedup 1.0000x reference)
//
#include <hip/hip_runtime.h>
#include <hip/hip_bf16.h>
#include <math.h>

// Problem constants
#define BB 8
#define TT 16
#define PP 14
#define LL 196      // P*P
#define HH 16
#define DD 64
#define DM 1024     // H*D
#define NS 16
#define T2 256      // T*T
#define LP1 197

using bf16x8 = __attribute__((ext_vector_type(8))) short;
using f32x4  = __attribute__((ext_vector_type(4))) float;

__device__ __forceinline__ float dot4(float4 a, float4 b) {
    return a.x*b.x + a.y*b.y + a.z*b.z + a.w*b.w;
}

// round-to-nearest-even bf16 pack of two finite fp32
__device__ __forceinline__ uint32_t pkbf(float lo, float hi) {
    uint32_t a = __builtin_bit_cast(uint32_t, lo);
    uint32_t b = __builtin_bit_cast(uint32_t, hi);
    a += 0x7FFFu + ((a >> 16) & 1u);
    b += 0x7FFFu + ((b >> 16) & 1u);
    return (a >> 16) | (b & 0xFFFF0000u);
}

// split pair (x,y) into hi/lo bf16 words: x ~= hi.x + lo.x exactly to ~2^-18
__device__ __forceinline__ void split2(float x, float y, uint32_t* h, uint32_t* lo) {
    const uint32_t hh = pkbf(x, y);
    const float hx = __builtin_bit_cast(float, hh << 16);
    const float hy = __builtin_bit_cast(float, hh & 0xFFFF0000u);
    *h = hh;
    *lo = pkbf(x - hx, y - hy);
}

__device__ __forceinline__ void pksplit(float4 p, float4 q, bf16x8& hi, bf16x8& lo) {
    uint32_t uh[4], ul[4];
    split2(p.x, p.y, &uh[0], &ul[0]);
    split2(p.z, p.w, &uh[1], &ul[1]);
    split2(q.x, q.y, &uh[2], &ul[2]);
    split2(q.z, q.w, &uh[3], &ul[3]);
    struct U4 { uint32_t v[4]; } th, tl;
    th.v[0] = uh[0]; th.v[1] = uh[1]; th.v[2] = uh[2]; th.v[3] = uh[3];
    tl.v[0] = ul[0]; tl.v[1] = ul[1]; tl.v[2] = ul[2]; tl.v[3] = ul[3];
    hi = __builtin_bit_cast(bf16x8, th);
    lo = __builtin_bit_cast(bf16x8, tl);
}

// ---------------------------------------------------------------------------
// Kernel 0: pre-split syno (16x1024 fp32) into hi/lo bf16 pair-words.
// ---------------------------------------------------------------------------
__global__ __launch_bounds__(256) void kprep(
        const float* __restrict__ syno,
        uint32_t* __restrict__ synoHi, uint32_t* __restrict__ synoLo) {
    const int i = blockIdx.x * 256 + threadIdx.x;   // 0..8191
    const float x = syno[2 * i], y = syno[2 * i + 1];
    uint32_t h, lo;
    split2(x, y, &h, &lo);
    synoHi[i] = h;
    synoLo[i] = lo;
}

// ---------------------------------------------------------------------------
// Kernel 1 (v11): R14's v10 + a compiler memory fence between the prefetch
// loads and the compute body. Loads cannot sink past an asm with "memory"
// clobber, so the depth-2 pipeline actually materializes (issue-early /
// counted-wait-late). VGPR rises ~44->~100; occupancy is LDS-limited
// (3 blocks/CU) so residency is unchanged.
// ---------------------------------------------------------------------------
__global__ __launch_bounds__(256) void k1_temporal(
        const float* __restrict__ qin, const float* __restrict__ kin,
        const float* __restrict__ tw,  const float* __restrict__ tbv,
        const uint32_t* __restrict__ synoHi, const uint32_t* __restrict__ synoLo,
        float* __restrict__ affRaw, float* __restrict__ SLout) {
    __shared__ __align__(16) float lds_c[16 * 260];   // [slot][pix]
    __shared__ __align__(16) float sl_part[4][16][16];

    const int bid = blockIdx.x, b = bid / LL, l = bid % LL;
    const int tid = threadIdx.x, wid = tid >> 6, lane = tid & 63;
    const int mrow = lane & 15;            // A-fragment row = frame
    const int g = lane >> 4;               // k-chunk group
    const int colb = lane & 15;
    const int oq = tid >> 4, ok = tid & 15;

    const size_t rowbase = ((size_t)(b*TT + mrow)*LP1 + 1 + l)*DM + g*8;
    f32x4 acc_sl = {0.f, 0.f, 0.f, 0.f};
    float accv = tbv[0];

    float4 A[2][4];
    uint4  S[2][4];

    // iteration mapping: it = pass*4 + jj*2 + hf; ch = 2*wid + 8*(it>>1) + (it&1)
#define K1_LOAD(BUF, IT) do {                                                  \
        const int ch_ = 2*wid + 8*((IT) >> 1) + ((IT) & 1);                    \
        const float* sp_ = ((IT) < 4) ? qin : kin;                             \
        const float* base_ = sp_ + rowbase + (size_t)(ch_ & 15) * DD;          \
        A[BUF][0] = *reinterpret_cast<const float4*>(base_);                   \
        A[BUF][1] = *reinterpret_cast<const float4*>(base_ + 4);               \
        A[BUF][2] = *reinterpret_cast<const float4*>(base_ + 32);              \
        A[BUF][3] = *reinterpret_cast<const float4*>(base_ + 36);              \
        if ((IT) >= 4) {                                                       \
            const int off_ = colb * 512 + (ch_ - 16) * 32 + g * 4;             \
            S[BUF][0] = *reinterpret_cast<const uint4*>(synoHi + off_);        \
            S[BUF][1] = *reinterpret_cast<const uint4*>(synoLo + off_);        \
            S[BUF][2] = *reinterpret_cast<const uint4*>(synoHi + off_ + 16);   \
            S[BUF][3] = *reinterpret_cast<const uint4*>(synoLo + off_ + 16);   \
        }                                                                      \
    } while (0)

#define K1_COMP(BUF, IT) do {                                                  \
        bf16x8 h1, l1, h2, l2;                                                 \
        pksplit(A[BUF][0], A[BUF][1], h1, l1);                                 \
        pksplit(A[BUF][2], A[BUF][3], h2, l2);                                 \
        f32x4 acc = {0.f, 0.f, 0.f, 0.f};                                      \
        acc = __builtin_amdgcn_mfma_f32_16x16x32_bf16(h1, h1, acc, 0, 0, 0);   \
        acc = __builtin_amdgcn_mfma_f32_16x16x32_bf16(h1, l1, acc, 0, 0, 0);   \
        acc = __builtin_amdgcn_mfma_f32_16x16x32_bf16(l1, h1, acc, 0, 0, 0);   \
        acc = __builtin_amdgcn_mfma_f32_16x16x32_bf16(h2, h2, acc, 0, 0, 0);   \
        acc = __builtin_amdgcn_mfma_f32_16x16x32_bf16(h2, l2, acc, 0, 0, 0);   \
        acc = __builtin_amdgcn_mfma_f32_16x16x32_bf16(l2, h2, acc, 0, 0, 0);   \
        if ((IT) >= 4) {                                                       \
            const bf16x8 sh1 = __builtin_bit_cast(bf16x8, S[BUF][0]);          \
            const bf16x8 sl1 = __builtin_bit_cast(bf16x8, S[BUF][1]);          \
            const bf16x8 sh2 = __builtin_bit_cast(bf16x8, S[BUF][2]);          \
            const bf16x8 sl2 = __builtin_bit_cast(bf16x8, S[BUF][3]);          \
            acc_sl = __builtin_amdgcn_mfma_f32_16x16x32_bf16(h1, sh1, acc_sl, 0, 0, 0); \
            acc_sl = __builtin_amdgcn_mfma_f32_16x16x32_bf16(h1, sl1, acc_sl, 0, 0, 0); \
            acc_sl = __builtin_amdgcn_mfma_f32_16x16x32_bf16(l1, sh1, acc_sl, 0, 0, 0); \
            acc_sl = __builtin_amdgcn_mfma_f32_16x16x32_bf16(h2, sh2, acc_sl, 0, 0, 0); \
            acc_sl = __builtin_amdgcn_mfma_f32_16x16x32_bf16(h2, sl2, acc_sl, 0, 0, 0); \
            acc_sl = __builtin_amdgcn_mfma_f32_16x16x32_bf16(l2, sh2, acc_sl, 0, 0, 0); \
        }                                                                      \
        /* softmax over cols (keys), no max pass (bounded logits) */           \
        const float e0 = __expf(acc[0] * 0.125f);                              \
        const float e1 = __expf(acc[1] * 0.125f);                              \
        const float e2 = __expf(acc[2] * 0.125f);                              \
        const float e3 = __expf(acc[3] * 0.125f);                              \
        float s0 = e0, s1 = e1, s2 = e2, s3 = e3;                              \
        _Pragma("unroll")                                                      \
        for (int msk = 1; msk < 16; msk <<= 1) {                               \
            s0 += __shfl_xor(s0, msk, 64);                                     \
            s1 += __shfl_xor(s1, msk, 64);                                     \
            s2 += __shfl_xor(s2, msk, 64);                                     \
            s3 += __shfl_xor(s3, msk, 64);                                     \
        }                                                                      \
        const int slot_ = 2*wid + 8*(((IT) >> 1) & 1) + ((IT) & 1);            \
        float* cp_ = lds_c + slot_ * 260;                                      \
        cp_[(g*4 + 0)*16 + colb] = e0 / s0;                                    \
        cp_[(g*4 + 1)*16 + colb] = e1 / s1;                                    \
        cp_[(g*4 + 2)*16 + colb] = e2 / s2;                                    \
        cp_[(g*4 + 3)*16 + colb] = e3 / s3;                                    \
    } while (0)

#define K1_CONV(PASS) do {                                                     \
        _Pragma("unroll")                                                      \
        for (int ky = 0; ky < 3; ++ky) {                                       \
            const int iq = oq + ky - 1;                                        \
            if (iq < 0 || iq > 15) continue;                                   \
            _Pragma("unroll")                                                  \
            for (int kx = 0; kx < 3; ++kx) {                                   \
                const int ik = ok + kx - 1;                                    \
                if (ik < 0 || ik > 15) continue;                               \
                const int pix = iq * 16 + ik;                                  \
                _Pragma("unroll")                                              \
                for (int s = 0; s < 16; ++s)                                   \
                    accv += lds_c[s * 260 + pix] * tw[((PASS)*16 + s)*9 + ky*3 + kx]; \
            }                                                                  \
        }                                                                      \
    } while (0)

    K1_LOAD(0, 0);
    #pragma unroll
    for (int it = 0; it < 8; ++it) {
        if (it < 7) {
            switch (it & 1) {     // compile-time after unroll
                case 0: K1_LOAD(1, it + 1); break;
                default: K1_LOAD(0, it + 1); break;
            }
        }
        // Pin the prefetch: loads may not sink below this point (the asm
        // may write any memory), so they issue before COMP and the compiler
        // emits a counted s_waitcnt at first use in the NEXT iteration.
        asm volatile("" ::: "memory");
        switch (it & 1) {
            case 0: K1_COMP(0, it); break;
            default: K1_COMP(1, it); break;
        }
        if (it == 3) {
            __syncthreads();
            K1_CONV(0);
            __syncthreads();
        }
    }

    // per-wave SL partials
    #pragma unroll
    for (int r = 0; r < 4; ++r)
        sl_part[wid][g * 4 + r][colb] = acc_sl[r];
    __syncthreads();
    K1_CONV(1);

    affRaw[(size_t)bid * T2 + tid] = accv;

    // SL reduce over the 4 waves + scaled write: thread = (t, q)
    {
        const int t = tid >> 4, qq = tid & 15;
        const float s = sl_part[0][t][qq] + sl_part[1][t][qq] +
                        sl_part[2][t][qq] + sl_part[3][t][qq];
        SLout[((size_t)(b * TT + t) * NS + qq) * LL + l] = s * 0.03125f;
    }
#undef K1_LOAD
#undef K1_COMP
#undef K1_CONV
}

// ---------------------------------------------------------------------------
// Kernel 2: LayerNorm + MLP (gelu exact) + residual. 4 rows per block.
// ---------------------------------------------------------------------------
__global__ __launch_bounds__(256) void k2_mlp(
        const float* __restrict__ affRaw,
        const float* __restrict__ lng, const float* __restrict__ lnb,
        const float* __restrict__ w1, const float* __restrict__ b1,
        const float* __restrict__ w2, const float* __restrict__ b2,
        float* __restrict__ affRes) {
    __shared__ __align__(16) float lx[4 * 256];
    __shared__ __align__(16) float lln[4 * 256];
    __shared__ __align__(16) float lg[4 * 256];
    const int tid = threadIdx.x;
    const int wave = tid >> 6, lane = tid & 63;
    const int i0 = blockIdx.x * 4;
    {
        const float* xr = affRaw + (size_t)(i0 + wave) * 256;
        float4 x = reinterpret_cast<const float4*>(xr)[lane];
        float sm = x.x + x.y + x.z + x.w;
        float ss = x.x * x.x + x.y * x.y + x.z * x.z + x.w * x.w;
        #pragma unroll
        for (int m = 1; m < 64; m <<= 1) {
            sm += __shfl_xor(sm, m, 64);
            ss += __shfl_xor(ss, m, 64);
        }
        const float mean = sm * (1.f / 256.f);
        const float var = ss * (1.f / 256.f) - mean * mean;
        const float inv = rsqrtf(var + 1e-5f);
        const float4 g4 = reinterpret_cast<const float4*>(lng)[lane];
        const float4 bb = reinterpret_cast<const float4*>(lnb)[lane];
        float4 ln;
        ln.x = (x.x - mean) * inv * g4.x + bb.x;
        ln.y = (x.y - mean) * inv * g4.y + bb.y;
        ln.z = (x.z - mean) * inv * g4.z + bb.z;
        ln.w = (x.w - mean) * inv * g4.w + bb.w;
        reinterpret_cast<float4*>(lx + wave * 256)[lane] = x;
        reinterpret_cast<float4*>(lln + wave * 256)[lane] = ln;
    }
    __syncthreads();
    const int j = tid;
    float a0 = 0.f, a1 = 0.f, a2 = 0.f, a3 = 0.f;
    {
        const float4* wr = reinterpret_cast<const float4*>(w1 + (size_t)j * 256);
        const float4* l0 = reinterpret_cast<const float4*>(lln);
        const float4* l1 = reinterpret_cast<const float4*>(lln + 256);
        const float4* l2 = reinterpret_cast<const float4*>(lln + 512);
        const float4* l3 = reinterpret_cast<const float4*>(lln + 768);
        #pragma unroll 8
        for (int m4 = 0; m4 < 64; ++m4) {
            const float4 w = wr[m4];
            a0 += dot4(w, l0[m4]); a1 += dot4(w, l1[m4]);
            a2 += dot4(w, l2[m4]); a3 += dot4(w, l3[m4]);
        }
    }
    const float bj = b1[j];
    const float kInvSqrt2 = 0.70710678118654752f;
    float h0 = a0 + bj, h1 = a1 + bj, h2 = a2 + bj, h3 = a3 + bj;
    lg[0 * 256 + j] = 0.5f * h0 * (1.f + erff(h0 * kInvSqrt2));
    lg[1 * 256 + j] = 0.5f * h1 * (1.f + erff(h1 * kInvSqrt2));
    lg[2 * 256 + j] = 0.5f * h2 * (1.f + erff(h2 * kInvSqrt2));
    lg[3 * 256 + j] = 0.5f * h3 * (1.f + erff(h3 * kInvSqrt2));
    __syncthreads();
    a0 = a1 = a2 = a3 = 0.f;
    {
        const float4* wr = reinterpret_cast<const float4*>(w2 + (size_t)j * 256);
        const float4* l0 = reinterpret_cast<const float4*>(lg);
        const float4* l1 = reinterpret_cast<const float4*>(lg + 256);
        const float4* l2 = reinterpret_cast<const float4*>(lg + 512);
        const float4* l3 = reinterpret_cast<const float4*>(lg + 768);
        #pragma unroll 8
        for (int m4 = 0; m4 < 64; ++m4) {
            const float4 w = wr[m4];
            a0 += dot4(w, l0[m4]); a1 += dot4(w, l1[m4]);
            a2 += dot4(w, l2[m4]); a3 += dot4(w, l3[m4]);
        }
    }
    const float b2j = b2[j];
    affRes[(size_t)(i0 + 0) * 256 + j] = lx[0 * 256 + j] + a0 + b2j;
    affRes[(size_t)(i0 + 1) * 256 + j] = lx[1 * 256 + j] + a1 + b2j;
    affRes[(size_t)(i0 + 2) * 256 + j] = lx[2 * 256 + j] + a2 + b2j;
    affRes[(size_t)(i0 + 3) * 256 + j] = lx[3 * 256 + j] + a3 + b2j;
}

// ---------------------------------------------------------------------------
// Kernel 3a: patch-grid 3x3 conv over 256 channels, split 64-ch per block.
// ---------------------------------------------------------------------------
__global__ __launch_bounds__(256) void k3a_pconv(
        const float* __restrict__ affRes, const float* __restrict__ pw,
        float* __restrict__ part) {
    __shared__ __align__(16) float lpw[576];
    const int b = blockIdx.x >> 2, cc = blockIdx.x & 3;
    const int tid = threadIdx.x;
    for (int idx = tid; idx < 576; idx += 256) {
        const int kk = idx / 64, c = idx & 63;
        lpw[kk * 64 + c] = pw[(size_t)(cc * 64 + c) * 9 + kk];
    }
    __syncthreads();
    if (tid < 196) {
        const int p1 = tid / 14, p2 = tid % 14;
        float s = 0.f;
        #pragma unroll
        for (int ky = 0; ky < 3; ++ky) {
            const int ip1 = p1 + ky - 1;
            if (ip1 < 0 || ip1 > 13) continue;
            #pragma unroll
            for (int kx = 0; kx < 3; ++kx) {
                const int ip2 = p2 + kx - 1;
                if (ip2 < 0 || ip2 > 13) continue;
                const float4* ar = reinterpret_cast<const float4*>(
                    affRes + (size_t)(b * LL + ip1 * 14 + ip2) * 256 + cc * 64);
                const float4* wr = reinterpret_cast<const float4*>(lpw + (ky * 3 + kx) * 64);
                #pragma unroll
                for (int c4 = 0; c4 < 16; ++c4) s += dot4(ar[c4], wr[c4]);
            }
        }
        part[(cc * 8 + b) * 196 + tid] = s;
    }
}

__global__ void k3b_yt(const float* __restrict__ part,
                       const float* __restrict__ pcb, float* __restrict__ out) {
    const int b = blockIdx.x, tid = threadIdx.x;
    if (tid < 196) {
        float s = pcb[0];
        #pragma unroll
        for (int cc = 0; cc < 4; ++cc) s += part[(cc * 8 + b) * 196 + tid];
        out[b * 196 + tid] = s;
    }
}

// Kernel 4b: softmax over l per (b,t,q) + sum over q -> WSUM[b,t,l]
__global__ __launch_bounds__(256) void k4b_softmax(
        const float* __restrict__ SL, float* __restrict__ WSUM) {
    __shared__ float lp[16 * 200];
    const int t = blockIdx.x, b = blockIdx.y;
    const int tid = threadIdx.x;
    const int qq = tid >> 4, j = tid & 15;
    const float* row = SL + (size_t)((b * TT + t) * NS + qq) * LL;
    float v[13];
    float m = -1e30f;
    #pragma unroll
    for (int i = 0; i < 13; ++i) {
        const int l = j + i * 16;
        v[i] = (l < LL) ? row[l] : -1e30f;
        m = fmaxf(m, v[i]);
    }
    #pragma unroll
    for (int msk = 1; msk < 16; msk <<= 1) m = fmaxf(m, __shfl_xor(m, msk, 64));
    float s = 0.f;
    #pragma unroll
    for (int i = 0; i < 13; ++i) {
        const int l = j + i * 16;
        v[i] = (l < LL) ? __expf(v[i] - m) : 0.f;
        s += v[i];
    }
    #pragma unroll
    for (int msk = 1; msk < 16; msk <<= 1) s += __shfl_xor(s, msk, 64);
    const float inv = 1.f / s;
    #pragma unroll
    for (int i = 0; i < 13; ++i) {
        const int l = j + i * 16;
        if (l < LL) lp[qq * 200 + l] = v[i] * inv;
    }
    __syncthreads();
    if (tid < LL) {
        float w = 0.f;
        #pragma unroll
        for (int qi = 0; qi < 16; ++qi) w += lp[qi * 200 + tid];
        WSUM[(size_t)(b * TT + t) * LL + tid] = w;
    }
}

// Kernel 4c: PS[bt][z][:] = sum over 98 rows of WSUM * v  (z-split over l)
__global__ __launch_bounds__(256) void k4c_vsum(
        const float* __restrict__ vin, const float* __restrict__ WSUM,
        float* __restrict__ PS) {
    __shared__ float lw[98];
    const int t = blockIdx.x, b = blockIdx.y, z = blockIdx.z;
    const int tid = threadIdx.x;
    const int bt = b * TT + t;
    if (tid < 98) lw[tid] = WSUM[(size_t)bt * LL + z * 98 + tid];
    __syncthreads();
    float4 acc = make_float4(0.f, 0.f, 0.f, 0.f);
    const float* vb = vin + ((size_t)bt * LP1 + 1 + z * 98) * DM + tid * 4;
    #pragma unroll 4
    for (int l = 0; l < 98; ++l) {
        const float4 v = *reinterpret_cast<const float4*>(vb + (size_t)l * DM);
        const float w = lw[l];
        acc.x += w * v.x; acc.y += w * v.y; acc.z += w * v.z; acc.w += w * v.w;
    }
    *reinterpret_cast<float4*>(PS + ((size_t)bt * 2 + z) * DM + tid * 4) = acc;
}

// Kernel 4d: y_s[b,w] = (1/256) * sum over 32 (t,z) partials
__global__ void k4d_ys(const float* __restrict__ PS, float* __restrict__ out) {
    const int i = blockIdx.x * 256 + threadIdx.x;   // 0..8191
    const int b = i >> 10, w = i & 1023;
    float s = 0.f;
    #pragma unroll
    for (int tz = 0; tz < 32; ++tz) s += PS[((size_t)b * 32 + tz) * DM + w];
    out[1568 + i] = s * (1.f / 256.f);
}

// ---------------------------------------------------------------------------
extern "C" void kernel_launch(void* const* d_in, const int* in_sizes, int n_in,
                              void* d_out, int out_size, void* d_ws, size_t ws_size,
                              hipStream_t stream) {
    const float* q    = (const float*)d_in[0];
    const float* k    = (const float*)d_in[1];
    const float* v    = (const float*)d_in[2];
    const float* syno = (const float*)d_in[3];
    const float* tw   = (const float*)d_in[4];
    const float* tbv  = (const float*)d_in[5];
    const float* lng  = (const float*)d_in[6];
    const float* lnb  = (const float*)d_in[7];
    const float* w1   = (const float*)d_in[8];
    const float* b1   = (const float*)d_in[9];
    const float* w2   = (const float*)d_in[10];
    const float* b2   = (const float*)d_in[11];
    const float* pw   = (const float*)d_in[12];
    const float* pcb  = (const float*)d_in[13];
    float* out = (float*)d_out;

    float* ws = (float*)d_ws;
    float* affRaw = ws;                 // 401408 floats (dead after k2)
    float* affRes = ws + 401408;        // 401408
    float* SL     = ws + 802816;        // 401408
    float* WSUM   = ws + 1204224;       // 25088
    float* part   = ws + 1229312;       // 6272
    uint32_t* synoHi = (uint32_t*)(ws + 1235584);   // 8192 u32
    uint32_t* synoLo = (uint32_t*)(ws + 1243776);   // 8192 u32
    float* PS     = ws;                 // 262144, aliases affRaw (k4c after k2)

    // syno pre-split (hi/lo bf16)
    hipLaunchKernelGGL(kprep, dim3(32), dim3(256), 0, stream, syno, synoHi, synoLo);
    // temporal path + fused spatial logits
    hipLaunchKernelGGL(k1_temporal, dim3(BB * LL), dim3(256), 0, stream,
                       q, k, tw, tbv, synoHi, synoLo, affRaw, SL);
    hipLaunchKernelGGL(k2_mlp, dim3(392), dim3(256), 0, stream,
                       affRaw, lng, lnb, w1, b1, w2, b2, affRes);
    hipLaunchKernelGGL(k3a_pconv, dim3(32), dim3(256), 0, stream,
                       affRes, pw, part);
    hipLaunchKernelGGL(k3b_yt, dim3(8), dim3(256), 0, stream, part, pcb, out);
    // spatial path (k4a fused into k1)
    hipLaunchKernelGGL(k4b_softmax, dim3(16, 8), dim3(256), 0, stream, SL, WSUM);
    hipLaunchKernelGGL(k4c_vsum, dim3(16, 8, 2), dim3(256), 0, stream, v, WSUM, PS);
    hipLaunchKernelGGL(k4d_ys, dim3(32), dim3(256), 0, stream, PS, out);
}

// Round 16
// 144.032 us; speedup vs baseline: 1.0155x; 1.0155x over previous
//
#include <hip/hip_runtime.h>
#include <hip/hip_bf16.h>
#include <math.h>

// Problem constants
#define BB 8
#define TT 16
#define PP 14
#define LL 196      // P*P
#define HH 16
#define DD 64
#define DM 1024     // H*D
#define NS 16
#define T2 256      // T*T
#define LP1 197

using bf16x8 = __attribute__((ext_vector_type(8))) short;
using f32x4  = __attribute__((ext_vector_type(4))) float;

__device__ __forceinline__ float dot4(float4 a, float4 b) {
    return a.x*b.x + a.y*b.y + a.z*b.z + a.w*b.w;
}

// round-to-nearest-even bf16 pack of two finite fp32
__device__ __forceinline__ uint32_t pkbf(float lo, float hi) {
    uint32_t a = __builtin_bit_cast(uint32_t, lo);
    uint32_t b = __builtin_bit_cast(uint32_t, hi);
    a += 0x7FFFu + ((a >> 16) & 1u);
    b += 0x7FFFu + ((b >> 16) & 1u);
    return (a >> 16) | (b & 0xFFFF0000u);
}

// split pair (x,y) into hi/lo bf16 words: x ~= hi.x + lo.x exactly to ~2^-18
__device__ __forceinline__ void split2(float x, float y, uint32_t* h, uint32_t* lo) {
    const uint32_t hh = pkbf(x, y);
    const float hx = __builtin_bit_cast(float, hh << 16);
    const float hy = __builtin_bit_cast(float, hh & 0xFFFF0000u);
    *h = hh;
    *lo = pkbf(x - hx, y - hy);
}

__device__ __forceinline__ void pksplit(float4 p, float4 q, bf16x8& hi, bf16x8& lo) {
    uint32_t uh[4], ul[4];
    split2(p.x, p.y, &uh[0], &ul[0]);
    split2(p.z, p.w, &uh[1], &ul[1]);
    split2(q.x, q.y, &uh[2], &ul[2]);
    split2(q.z, q.w, &uh[3], &ul[3]);
    struct U4 { uint32_t v[4]; } th, tl;
    th.v[0] = uh[0]; th.v[1] = uh[1]; th.v[2] = uh[2]; th.v[3] = uh[3];
    tl.v[0] = ul[0]; tl.v[1] = ul[1]; tl.v[2] = ul[2]; tl.v[3] = ul[3];
    hi = __builtin_bit_cast(bf16x8, th);
    lo = __builtin_bit_cast(bf16x8, tl);
}

// ---------------------------------------------------------------------------
// Kernel 0: pre-split syno (16x1024 fp32) into hi/lo bf16 pair-words.
// ---------------------------------------------------------------------------
__global__ __launch_bounds__(256) void kprep(
        const float* __restrict__ syno,
        uint32_t* __restrict__ synoHi, uint32_t* __restrict__ synoLo) {
    const int i = blockIdx.x * 256 + threadIdx.x;   // 0..8191
    const float x = syno[2 * i], y = syno[2 * i + 1];
    uint32_t h, lo;
    split2(x, y, &h, &lo);
    synoHi[i] = h;
    synoLo[i] = lo;
}

// ---------------------------------------------------------------------------
// Kernel 1 (v10, R14-best): depth-2 structure, two conv passes, no softmax
// max-pass (bounded logits). 91-92us — pinned across 9 structural variants
// by an effective-read-BW floor (~2.2 TB/s); all pipes <30%.
// ---------------------------------------------------------------------------
__global__ __launch_bounds__(256) void k1_temporal(
        const float* __restrict__ qin, const float* __restrict__ kin,
        const float* __restrict__ tw,  const float* __restrict__ tbv,
        const uint32_t* __restrict__ synoHi, const uint32_t* __restrict__ synoLo,
        float* __restrict__ affRaw, float* __restrict__ SLout) {
    __shared__ __align__(16) float lds_c[16 * 260];   // [slot][pix]
    __shared__ __align__(16) float sl_part[4][16][16];

    const int bid = blockIdx.x, b = bid / LL, l = bid % LL;
    const int tid = threadIdx.x, wid = tid >> 6, lane = tid & 63;
    const int mrow = lane & 15;            // A-fragment row = frame
    const int g = lane >> 4;               // k-chunk group
    const int colb = lane & 15;
    const int oq = tid >> 4, ok = tid & 15;

    const size_t rowbase = ((size_t)(b*TT + mrow)*LP1 + 1 + l)*DM + g*8;
    f32x4 acc_sl = {0.f, 0.f, 0.f, 0.f};
    float accv = tbv[0];

    float4 A[2][4];
    uint4  S[2][4];

    // iteration mapping: it = pass*4 + jj*2 + hf; ch = 2*wid + 8*(it>>1) + (it&1)
#define K1_LOAD(BUF, IT) do {                                                  \
        const int ch_ = 2*wid + 8*((IT) >> 1) + ((IT) & 1);                    \
        const float* sp_ = ((IT) < 4) ? qin : kin;                             \
        const float* base_ = sp_ + rowbase + (size_t)(ch_ & 15) * DD;          \
        A[BUF][0] = *reinterpret_cast<const float4*>(base_);                   \
        A[BUF][1] = *reinterpret_cast<const float4*>(base_ + 4);               \
        A[BUF][2] = *reinterpret_cast<const float4*>(base_ + 32);              \
        A[BUF][3] = *reinterpret_cast<const float4*>(base_ + 36);              \
        if ((IT) >= 4) {                                                       \
            const int off_ = colb * 512 + (ch_ - 16) * 32 + g * 4;             \
            S[BUF][0] = *reinterpret_cast<const uint4*>(synoHi + off_);        \
            S[BUF][1] = *reinterpret_cast<const uint4*>(synoLo + off_);        \
            S[BUF][2] = *reinterpret_cast<const uint4*>(synoHi + off_ + 16);   \
            S[BUF][3] = *reinterpret_cast<const uint4*>(synoLo + off_ + 16);   \
        }                                                                      \
    } while (0)

#define K1_COMP(BUF, IT) do {                                                  \
        bf16x8 h1, l1, h2, l2;                                                 \
        pksplit(A[BUF][0], A[BUF][1], h1, l1);                                 \
        pksplit(A[BUF][2], A[BUF][3], h2, l2);                                 \
        f32x4 acc = {0.f, 0.f, 0.f, 0.f};                                      \
        acc = __builtin_amdgcn_mfma_f32_16x16x32_bf16(h1, h1, acc, 0, 0, 0);   \
        acc = __builtin_amdgcn_mfma_f32_16x16x32_bf16(h1, l1, acc, 0, 0, 0);   \
        acc = __builtin_amdgcn_mfma_f32_16x16x32_bf16(l1, h1, acc, 0, 0, 0);   \
        acc = __builtin_amdgcn_mfma_f32_16x16x32_bf16(h2, h2, acc, 0, 0, 0);   \
        acc = __builtin_amdgcn_mfma_f32_16x16x32_bf16(h2, l2, acc, 0, 0, 0);   \
        acc = __builtin_amdgcn_mfma_f32_16x16x32_bf16(l2, h2, acc, 0, 0, 0);   \
        if ((IT) >= 4) {                                                       \
            const bf16x8 sh1 = __builtin_bit_cast(bf16x8, S[BUF][0]);          \
            const bf16x8 sl1 = __builtin_bit_cast(bf16x8, S[BUF][1]);          \
            const bf16x8 sh2 = __builtin_bit_cast(bf16x8, S[BUF][2]);          \
            const bf16x8 sl2 = __builtin_bit_cast(bf16x8, S[BUF][3]);          \
            acc_sl = __builtin_amdgcn_mfma_f32_16x16x32_bf16(h1, sh1, acc_sl, 0, 0, 0); \
            acc_sl = __builtin_amdgcn_mfma_f32_16x16x32_bf16(h1, sl1, acc_sl, 0, 0, 0); \
            acc_sl = __builtin_amdgcn_mfma_f32_16x16x32_bf16(l1, sh1, acc_sl, 0, 0, 0); \
            acc_sl = __builtin_amdgcn_mfma_f32_16x16x32_bf16(h2, sh2, acc_sl, 0, 0, 0); \
            acc_sl = __builtin_amdgcn_mfma_f32_16x16x32_bf16(h2, sl2, acc_sl, 0, 0, 0); \
            acc_sl = __builtin_amdgcn_mfma_f32_16x16x32_bf16(l2, sh2, acc_sl, 0, 0, 0); \
        }                                                                      \
        /* softmax over cols (keys), no max pass (bounded logits) */           \
        const float e0 = __expf(acc[0] * 0.125f);                              \
        const float e1 = __expf(acc[1] * 0.125f);                              \
        const float e2 = __expf(acc[2] * 0.125f);                              \
        const float e3 = __expf(acc[3] * 0.125f);                              \
        float s0 = e0, s1 = e1, s2 = e2, s3 = e3;                              \
        _Pragma("unroll")                                                      \
        for (int msk = 1; msk < 16; msk <<= 1) {                               \
            s0 += __shfl_xor(s0, msk, 64);                                     \
            s1 += __shfl_xor(s1, msk, 64);                                     \
            s2 += __shfl_xor(s2, msk, 64);                                     \
            s3 += __shfl_xor(s3, msk, 64);                                     \
        }                                                                      \
        const int slot_ = 2*wid + 8*(((IT) >> 1) & 1) + ((IT) & 1);            \
        float* cp_ = lds_c + slot_ * 260;                                      \
        cp_[(g*4 + 0)*16 + colb] = e0 / s0;                                    \
        cp_[(g*4 + 1)*16 + colb] = e1 / s1;                                    \
        cp_[(g*4 + 2)*16 + colb] = e2 / s2;                                    \
        cp_[(g*4 + 3)*16 + colb] = e3 / s3;                                    \
    } while (0)

#define K1_CONV(PASS) do {                                                     \
        _Pragma("unroll")                                                      \
        for (int ky = 0; ky < 3; ++ky) {                                       \
            const int iq = oq + ky - 1;                                        \
            if (iq < 0 || iq > 15) continue;                                   \
            _Pragma("unroll")                                                  \
            for (int kx = 0; kx < 3; ++kx) {                                   \
                const int ik = ok + kx - 1;                                    \
                if (ik < 0 || ik > 15) continue;                               \
                const int pix = iq * 16 + ik;                                  \
                _Pragma("unroll")                                              \
                for (int s = 0; s < 16; ++s)                                   \
                    accv += lds_c[s * 260 + pix] * tw[((PASS)*16 + s)*9 + ky*3 + kx]; \
            }                                                                  \
        }                                                                      \
    } while (0)

    K1_LOAD(0, 0);
    #pragma unroll
    for (int it = 0; it < 8; ++it) {
        if (it < 7) {
            switch (it & 1) {     // compile-time after unroll
                case 0: K1_LOAD(1, it + 1); break;
                default: K1_LOAD(0, it + 1); break;
            }
        }
        switch (it & 1) {
            case 0: K1_COMP(0, it); break;
            default: K1_COMP(1, it); break;
        }
        if (it == 3) {
            __syncthreads();
            K1_CONV(0);
            __syncthreads();
        }
    }

    // per-wave SL partials
    #pragma unroll
    for (int r = 0; r < 4; ++r)
        sl_part[wid][g * 4 + r][colb] = acc_sl[r];
    __syncthreads();
    K1_CONV(1);

    affRaw[(size_t)bid * T2 + tid] = accv;

    // SL reduce over the 4 waves + scaled write: thread = (t, q)
    {
        const int t = tid >> 4, qq = tid & 15;
        const float s = sl_part[0][t][qq] + sl_part[1][t][qq] +
                        sl_part[2][t][qq] + sl_part[3][t][qq];
        SLout[((size_t)(b * TT + t) * NS + qq) * LL + l] = s * 0.03125f;
    }
#undef K1_LOAD
#undef K1_COMP
#undef K1_CONV
}

// ---------------------------------------------------------------------------
// Kernel 2: LayerNorm + MLP (gelu exact) + residual. 4 rows per block.
// ---------------------------------------------------------------------------
__global__ __launch_bounds__(256) void k2_mlp(
        const float* __restrict__ affRaw,
        const float* __restrict__ lng, const float* __restrict__ lnb,
        const float* __restrict__ w1, const float* __restrict__ b1,
        const float* __restrict__ w2, const float* __restrict__ b2,
        float* __restrict__ affRes) {
    __shared__ __align__(16) float lx[4 * 256];
    __shared__ __align__(16) float lln[4 * 256];
    __shared__ __align__(16) float lg[4 * 256];
    const int tid = threadIdx.x;
    const int wave = tid >> 6, lane = tid & 63;
    const int i0 = blockIdx.x * 4;
    {
        const float* xr = affRaw + (size_t)(i0 + wave) * 256;
        float4 x = reinterpret_cast<const float4*>(xr)[lane];
        float sm = x.x + x.y + x.z + x.w;
        float ss = x.x * x.x + x.y * x.y + x.z * x.z + x.w * x.w;
        #pragma unroll
        for (int m = 1; m < 64; m <<= 1) {
            sm += __shfl_xor(sm, m, 64);
            ss += __shfl_xor(ss, m, 64);
        }
        const float mean = sm * (1.f / 256.f);
        const float var = ss * (1.f / 256.f) - mean * mean;
        const float inv = rsqrtf(var + 1e-5f);
        const float4 g4 = reinterpret_cast<const float4*>(lng)[lane];
        const float4 bb = reinterpret_cast<const float4*>(lnb)[lane];
        float4 ln;
        ln.x = (x.x - mean) * inv * g4.x + bb.x;
        ln.y = (x.y - mean) * inv * g4.y + bb.y;
        ln.z = (x.z - mean) * inv * g4.z + bb.z;
        ln.w = (x.w - mean) * inv * g4.w + bb.w;
        reinterpret_cast<float4*>(lx + wave * 256)[lane] = x;
        reinterpret_cast<float4*>(lln + wave * 256)[lane] = ln;
    }
    __syncthreads();
    const int j = tid;
    float a0 = 0.f, a1 = 0.f, a2 = 0.f, a3 = 0.f;
    {
        const float4* wr = reinterpret_cast<const float4*>(w1 + (size_t)j * 256);
        const float4* l0 = reinterpret_cast<const float4*>(lln);
        const float4* l1 = reinterpret_cast<const float4*>(lln + 256);
        const float4* l2 = reinterpret_cast<const float4*>(lln + 512);
        const float4* l3 = reinterpret_cast<const float4*>(lln + 768);
        #pragma unroll 8
        for (int m4 = 0; m4 < 64; ++m4) {
            const float4 w = wr[m4];
            a0 += dot4(w, l0[m4]); a1 += dot4(w, l1[m4]);
            a2 += dot4(w, l2[m4]); a3 += dot4(w, l3[m4]);
        }
    }
    const float bj = b1[j];
    const float kInvSqrt2 = 0.70710678118654752f;
    float h0 = a0 + bj, h1 = a1 + bj, h2 = a2 + bj, h3 = a3 + bj;
    lg[0 * 256 + j] = 0.5f * h0 * (1.f + erff(h0 * kInvSqrt2));
    lg[1 * 256 + j] = 0.5f * h1 * (1.f + erff(h1 * kInvSqrt2));
    lg[2 * 256 + j] = 0.5f * h2 * (1.f + erff(h2 * kInvSqrt2));
    lg[3 * 256 + j] = 0.5f * h3 * (1.f + erff(h3 * kInvSqrt2));
    __syncthreads();
    a0 = a1 = a2 = a3 = 0.f;
    {
        const float4* wr = reinterpret_cast<const float4*>(w2 + (size_t)j * 256);
        const float4* l0 = reinterpret_cast<const float4*>(lg);
        const float4* l1 = reinterpret_cast<const float4*>(lg + 256);
        const float4* l2 = reinterpret_cast<const float4*>(lg + 512);
        const float4* l3 = reinterpret_cast<const float4*>(lg + 768);
        #pragma unroll 8
        for (int m4 = 0; m4 < 64; ++m4) {
            const float4 w = wr[m4];
            a0 += dot4(w, l0[m4]); a1 += dot4(w, l1[m4]);
            a2 += dot4(w, l2[m4]); a3 += dot4(w, l3[m4]);
        }
    }
    const float b2j = b2[j];
    affRes[(size_t)(i0 + 0) * 256 + j] = lx[0 * 256 + j] + a0 + b2j;
    affRes[(size_t)(i0 + 1) * 256 + j] = lx[1 * 256 + j] + a1 + b2j;
    affRes[(size_t)(i0 + 2) * 256 + j] = lx[2 * 256 + j] + a2 + b2j;
    affRes[(size_t)(i0 + 3) * 256 + j] = lx[3 * 256 + j] + a3 + b2j;
}

// ---------------------------------------------------------------------------
// Kernel 3a: patch-grid 3x3 conv over 256 channels, split 64-ch per block.
// ---------------------------------------------------------------------------
__global__ __launch_bounds__(256) void k3a_pconv(
        const float* __restrict__ affRes, const float* __restrict__ pw,
        float* __restrict__ part) {
    __shared__ __align__(16) float lpw[576];
    const int b = blockIdx.x >> 2, cc = blockIdx.x & 3;
    const int tid = threadIdx.x;
    for (int idx = tid; idx < 576; idx += 256) {
        const int kk = idx / 64, c = idx & 63;
        lpw[kk * 64 + c] = pw[(size_t)(cc * 64 + c) * 9 + kk];
    }
    __syncthreads();
    if (tid < 196) {
        const int p1 = tid / 14, p2 = tid % 14;
        float s = 0.f;
        #pragma unroll
        for (int ky = 0; ky < 3; ++ky) {
            const int ip1 = p1 + ky - 1;
            if (ip1 < 0 || ip1 > 13) continue;
            #pragma unroll
            for (int kx = 0; kx < 3; ++kx) {
                const int ip2 = p2 + kx - 1;
                if (ip2 < 0 || ip2 > 13) continue;
                const float4* ar = reinterpret_cast<const float4*>(
                    affRes + (size_t)(b * LL + ip1 * 14 + ip2) * 256 + cc * 64);
                const float4* wr = reinterpret_cast<const float4*>(lpw + (ky * 3 + kx) * 64);
                #pragma unroll
                for (int c4 = 0; c4 < 16; ++c4) s += dot4(ar[c4], wr[c4]);
            }
        }
        part[(cc * 8 + b) * 196 + tid] = s;
    }
}

__global__ void k3b_yt(const float* __restrict__ part,
                       const float* __restrict__ pcb, float* __restrict__ out) {
    const int b = blockIdx.x, tid = threadIdx.x;
    if (tid < 196) {
        float s = pcb[0];
        #pragma unroll
        for (int cc = 0; cc < 4; ++cc) s += part[(cc * 8 + b) * 196 + tid];
        out[b * 196 + tid] = s;
    }
}

// ---------------------------------------------------------------------------
// Kernel 4bc (merged k4b+k4c, validated in R13): per (t,b,z): softmax over l
// for all 16 synos + q-sum -> ws[196] in LDS, then PV over this z's 98 rows.
// ---------------------------------------------------------------------------
__global__ __launch_bounds__(256) void k4bc(
        const float* __restrict__ SL, const float* __restrict__ vin,
        float* __restrict__ PS) {
    __shared__ float lp[16 * 200];
    __shared__ float ws[196];
    const int t = blockIdx.x, b = blockIdx.y, z = blockIdx.z;
    const int tid = threadIdx.x;
    const int qq = tid >> 4, j = tid & 15;
    const float* row = SL + (size_t)((b * TT + t) * NS + qq) * LL;
    float v[13];
    float m = -1e30f;
    #pragma unroll
    for (int i = 0; i < 13; ++i) {
        const int l = j + i * 16;
        v[i] = (l < LL) ? row[l] : -1e30f;
        m = fmaxf(m, v[i]);
    }
    #pragma unroll
    for (int msk = 1; msk < 16; msk <<= 1) m = fmaxf(m, __shfl_xor(m, msk, 64));
    float s = 0.f;
    #pragma unroll
    for (int i = 0; i < 13; ++i) {
        const int l = j + i * 16;
        v[i] = (l < LL) ? __expf(v[i] - m) : 0.f;
        s += v[i];
    }
    #pragma unroll
    for (int msk = 1; msk < 16; msk <<= 1) s += __shfl_xor(s, msk, 64);
    const float inv = 1.f / s;
    #pragma unroll
    for (int i = 0; i < 13; ++i) {
        const int l = j + i * 16;
        if (l < LL) lp[qq * 200 + l] = v[i] * inv;
    }
    __syncthreads();
    if (tid < LL) {
        float w = 0.f;
        #pragma unroll
        for (int qi = 0; qi < 16; ++qi) w += lp[qi * 200 + tid];
        ws[tid] = w;
    }
    __syncthreads();
    const int bt = b * TT + t;
    float4 acc = make_float4(0.f, 0.f, 0.f, 0.f);
    const float* vb = vin + ((size_t)bt * LP1 + 1 + z * 98) * DM + tid * 4;
    const float* wz = ws + z * 98;
    #pragma unroll 4
    for (int l = 0; l < 98; ++l) {
        const float4 vv = *reinterpret_cast<const float4*>(vb + (size_t)l * DM);
        const float w = wz[l];
        acc.x += w * vv.x; acc.y += w * vv.y; acc.z += w * vv.z; acc.w += w * vv.w;
    }
    *reinterpret_cast<float4*>(PS + ((size_t)bt * 2 + z) * DM + tid * 4) = acc;
}

// Kernel 4d: y_s[b,w] = (1/256) * sum over 32 (t,z) partials
__global__ void k4d_ys(const float* __restrict__ PS, float* __restrict__ out) {
    const int i = blockIdx.x * 256 + threadIdx.x;   // 0..8191
    const int b = i >> 10, w = i & 1023;
    float s = 0.f;
    #pragma unroll
    for (int tz = 0; tz < 32; ++tz) s += PS[((size_t)b * 32 + tz) * DM + w];
    out[1568 + i] = s * (1.f / 256.f);
}

// ---------------------------------------------------------------------------
extern "C" void kernel_launch(void* const* d_in, const int* in_sizes, int n_in,
                              void* d_out, int out_size, void* d_ws, size_t ws_size,
                              hipStream_t stream) {
    const float* q    = (const float*)d_in[0];
    const float* k    = (const float*)d_in[1];
    const float* v    = (const float*)d_in[2];
    const float* syno = (const float*)d_in[3];
    const float* tw   = (const float*)d_in[4];
    const float* tbv  = (const float*)d_in[5];
    const float* lng  = (const float*)d_in[6];
    const float* lnb  = (const float*)d_in[7];
    const float* w1   = (const float*)d_in[8];
    const float* b1   = (const float*)d_in[9];
    const float* w2   = (const float*)d_in[10];
    const float* b2   = (const float*)d_in[11];
    const float* pw   = (const float*)d_in[12];
    const float* pcb  = (const float*)d_in[13];
    float* out = (float*)d_out;

    float* ws = (float*)d_ws;
    float* affRaw = ws;                 // 401408 floats (dead after k2)
    float* affRes = ws + 401408;        // 401408
    float* SL     = ws + 802816;        // 401408
    float* part   = ws + 1229312;       // 6272
    uint32_t* synoHi = (uint32_t*)(ws + 1235584);   // 8192 u32
    uint32_t* synoLo = (uint32_t*)(ws + 1243776);   // 8192 u32
    float* PS     = ws;                 // 262144, aliases affRaw (k4bc after k2)

    // syno pre-split (hi/lo bf16)
    hipLaunchKernelGGL(kprep, dim3(32), dim3(256), 0, stream, syno, synoHi, synoLo);
    // temporal path + fused spatial logits
    hipLaunchKernelGGL(k1_temporal, dim3(BB * LL), dim3(256), 0, stream,
                       q, k, tw, tbv, synoHi, synoLo, affRaw, SL);
    hipLaunchKernelGGL(k2_mlp, dim3(392), dim3(256), 0, stream,
                       affRaw, lng, lnb, w1, b1, w2, b2, affRes);
    hipLaunchKernelGGL(k3a_pconv, dim3(32), dim3(256), 0, stream,
                       affRes, pw, part);
    hipLaunchKernelGGL(k3b_yt, dim3(8), dim3(256), 0, stream, part, pcb, out);
    // spatial path (k4a fused into k1; k4b+k4c merged, full parallelism)
    hipLaunchKernelGGL(k4bc, dim3(16, 8, 2), dim3(256), 0, stream, SL, v, PS);
    hipLaunchKernelGGL(k4d_ys, dim3(32), dim3(256), 0, stream, PS, out);
}

// Round 17
// 132.242 us; speedup vs baseline: 1.1060x; 1.0892x over previous
//
#include <hip/hip_runtime.h>
#include <hip/hip_bf16.h>
#include <math.h>

// Problem constants
#define BB 8
#define TT 16
#define PP 14
#define LL 196      // P*P
#define HH 16
#define DD 64
#define DM 1024     // H*D
#define NS 16
#define T2 256      // T*T
#define LP1 197

using bf16x8 = __attribute__((ext_vector_type(8))) short;
using f32x4  = __attribute__((ext_vector_type(4))) float;

__device__ __forceinline__ float dot4(float4 a, float4 b) {
    return a.x*b.x + a.y*b.y + a.z*b.z + a.w*b.w;
}

// round-to-nearest-even bf16 pack of two finite fp32
__device__ __forceinline__ uint32_t pkbf(float lo, float hi) {
    uint32_t a = __builtin_bit_cast(uint32_t, lo);
    uint32_t b = __builtin_bit_cast(uint32_t, hi);
    a += 0x7FFFu + ((a >> 16) & 1u);
    b += 0x7FFFu + ((b >> 16) & 1u);
    return (a >> 16) | (b & 0xFFFF0000u);
}

// split pair (x,y) into hi/lo bf16 words: x ~= hi.x + lo.x exactly to ~2^-18
__device__ __forceinline__ void split2(float x, float y, uint32_t* h, uint32_t* lo) {
    const uint32_t hh = pkbf(x, y);
    const float hx = __builtin_bit_cast(float, hh << 16);
    const float hy = __builtin_bit_cast(float, hh & 0xFFFF0000u);
    *h = hh;
    *lo = pkbf(x - hx, y - hy);
}

__device__ __forceinline__ void pksplit(float4 p, float4 q, bf16x8& hi, bf16x8& lo) {
    uint32_t uh[4], ul[4];
    split2(p.x, p.y, &uh[0], &ul[0]);
    split2(p.z, p.w, &uh[1], &ul[1]);
    split2(q.x, q.y, &uh[2], &ul[2]);
    split2(q.z, q.w, &uh[3], &ul[3]);
    struct U4 { uint32_t v[4]; } th, tl;
    th.v[0] = uh[0]; th.v[1] = uh[1]; th.v[2] = uh[2]; th.v[3] = uh[3];
    tl.v[0] = ul[0]; tl.v[1] = ul[1]; tl.v[2] = ul[2]; tl.v[3] = ul[3];
    hi = __builtin_bit_cast(bf16x8, th);
    lo = __builtin_bit_cast(bf16x8, tl);
}

// ---------------------------------------------------------------------------
// Kernel 0: pre-split syno (16x1024 fp32) into hi/lo bf16 pair-words.
// ---------------------------------------------------------------------------
__global__ __launch_bounds__(256) void kprep(
        const float* __restrict__ syno,
        uint32_t* __restrict__ synoHi, uint32_t* __restrict__ synoLo) {
    const int i = blockIdx.x * 256 + threadIdx.x;   // 0..8191
    const float x = syno[2 * i], y = syno[2 * i + 1];
    uint32_t h, lo;
    split2(x, y, &h, &lo);
    synoHi[i] = h;
    synoLo[i] = lo;
}

// Kernel 0b: pre-split w1 and w2 (256x256 each) into hi/lo bf16 pair-words.
__global__ __launch_bounds__(256) void kprep_w(
        const float* __restrict__ w1, const float* __restrict__ w2,
        uint32_t* __restrict__ w1h, uint32_t* __restrict__ w1l,
        uint32_t* __restrict__ w2h, uint32_t* __restrict__ w2l) {
    const int i = blockIdx.x * 256 + threadIdx.x;   // 0..32767
    uint32_t h, lo;
    split2(w1[2 * i], w1[2 * i + 1], &h, &lo);
    w1h[i] = h; w1l[i] = lo;
    split2(w2[2 * i], w2[2 * i + 1], &h, &lo);
    w2h[i] = h; w2l[i] = lo;
}

// ---------------------------------------------------------------------------
// Kernel 1 (v10, R14-best): depth-2 structure, two conv passes, no softmax
// max-pass (bounded logits). ~92us — pinned across 9 structural variants
// by an effective-read-BW floor; all pipes <30%. Frozen.
// ---------------------------------------------------------------------------
__global__ __launch_bounds__(256) void k1_temporal(
        const float* __restrict__ qin, const float* __restrict__ kin,
        const float* __restrict__ tw,  const float* __restrict__ tbv,
        const uint32_t* __restrict__ synoHi, const uint32_t* __restrict__ synoLo,
        float* __restrict__ affRaw, float* __restrict__ SLout) {
    __shared__ __align__(16) float lds_c[16 * 260];   // [slot][pix]
    __shared__ __align__(16) float sl_part[4][16][16];

    const int bid = blockIdx.x, b = bid / LL, l = bid % LL;
    const int tid = threadIdx.x, wid = tid >> 6, lane = tid & 63;
    const int mrow = lane & 15;            // A-fragment row = frame
    const int g = lane >> 4;               // k-chunk group
    const int colb = lane & 15;
    const int oq = tid >> 4, ok = tid & 15;

    const size_t rowbase = ((size_t)(b*TT + mrow)*LP1 + 1 + l)*DM + g*8;
    f32x4 acc_sl = {0.f, 0.f, 0.f, 0.f};
    float accv = tbv[0];

    float4 A[2][4];
    uint4  S[2][4];

#define K1_LOAD(BUF, IT) do {                                                  \
        const int ch_ = 2*wid + 8*((IT) >> 1) + ((IT) & 1);                    \
        const float* sp_ = ((IT) < 4) ? qin : kin;                             \
        const float* base_ = sp_ + rowbase + (size_t)(ch_ & 15) * DD;          \
        A[BUF][0] = *reinterpret_cast<const float4*>(base_);                   \
        A[BUF][1] = *reinterpret_cast<const float4*>(base_ + 4);               \
        A[BUF][2] = *reinterpret_cast<const float4*>(base_ + 32);              \
        A[BUF][3] = *reinterpret_cast<const float4*>(base_ + 36);              \
        if ((IT) >= 4) {                                                       \
            const int off_ = colb * 512 + (ch_ - 16) * 32 + g * 4;             \
            S[BUF][0] = *reinterpret_cast<const uint4*>(synoHi + off_);        \
            S[BUF][1] = *reinterpret_cast<const uint4*>(synoLo + off_);        \
            S[BUF][2] = *reinterpret_cast<const uint4*>(synoHi + off_ + 16);   \
            S[BUF][3] = *reinterpret_cast<const uint4*>(synoLo + off_ + 16);   \
        }                                                                      \
    } while (0)

#define K1_COMP(BUF, IT) do {                                                  \
        bf16x8 h1, l1, h2, l2;                                                 \
        pksplit(A[BUF][0], A[BUF][1], h1, l1);                                 \
        pksplit(A[BUF][2], A[BUF][3], h2, l2);                                 \
        f32x4 acc = {0.f, 0.f, 0.f, 0.f};                                      \
        acc = __builtin_amdgcn_mfma_f32_16x16x32_bf16(h1, h1, acc, 0, 0, 0);   \
        acc = __builtin_amdgcn_mfma_f32_16x16x32_bf16(h1, l1, acc, 0, 0, 0);   \
        acc = __builtin_amdgcn_mfma_f32_16x16x32_bf16(l1, h1, acc, 0, 0, 0);   \
        acc = __builtin_amdgcn_mfma_f32_16x16x32_bf16(h2, h2, acc, 0, 0, 0);   \
        acc = __builtin_amdgcn_mfma_f32_16x16x32_bf16(h2, l2, acc, 0, 0, 0);   \
        acc = __builtin_amdgcn_mfma_f32_16x16x32_bf16(l2, h2, acc, 0, 0, 0);   \
        if ((IT) >= 4) {                                                       \
            const bf16x8 sh1 = __builtin_bit_cast(bf16x8, S[BUF][0]);          \
            const bf16x8 sl1 = __builtin_bit_cast(bf16x8, S[BUF][1]);          \
            const bf16x8 sh2 = __builtin_bit_cast(bf16x8, S[BUF][2]);          \
            const bf16x8 sl2 = __builtin_bit_cast(bf16x8, S[BUF][3]);          \
            acc_sl = __builtin_amdgcn_mfma_f32_16x16x32_bf16(h1, sh1, acc_sl, 0, 0, 0); \
            acc_sl = __builtin_amdgcn_mfma_f32_16x16x32_bf16(h1, sl1, acc_sl, 0, 0, 0); \
            acc_sl = __builtin_amdgcn_mfma_f32_16x16x32_bf16(l1, sh1, acc_sl, 0, 0, 0); \
            acc_sl = __builtin_amdgcn_mfma_f32_16x16x32_bf16(h2, sh2, acc_sl, 0, 0, 0); \
            acc_sl = __builtin_amdgcn_mfma_f32_16x16x32_bf16(h2, sl2, acc_sl, 0, 0, 0); \
            acc_sl = __builtin_amdgcn_mfma_f32_16x16x32_bf16(l2, sh2, acc_sl, 0, 0, 0); \
        }                                                                      \
        const float e0 = __expf(acc[0] * 0.125f);                              \
        const float e1 = __expf(acc[1] * 0.125f);                              \
        const float e2 = __expf(acc[2] * 0.125f);                              \
        const float e3 = __expf(acc[3] * 0.125f);                              \
        float s0 = e0, s1 = e1, s2 = e2, s3 = e3;                              \
        _Pragma("unroll")                                                      \
        for (int msk = 1; msk < 16; msk <<= 1) {                               \
            s0 += __shfl_xor(s0, msk, 64);                                     \
            s1 += __shfl_xor(s1, msk, 64);                                     \
            s2 += __shfl_xor(s2, msk, 64);                                     \
            s3 += __shfl_xor(s3, msk, 64);                                     \
        }                                                                      \
        const int slot_ = 2*wid + 8*(((IT) >> 1) & 1) + ((IT) & 1);            \
        float* cp_ = lds_c + slot_ * 260;                                      \
        cp_[(g*4 + 0)*16 + colb] = e0 / s0;                                    \
        cp_[(g*4 + 1)*16 + colb] = e1 / s1;                                    \
        cp_[(g*4 + 2)*16 + colb] = e2 / s2;                                    \
        cp_[(g*4 + 3)*16 + colb] = e3 / s3;                                    \
    } while (0)

#define K1_CONV(PASS) do {                                                     \
        _Pragma("unroll")                                                      \
        for (int ky = 0; ky < 3; ++ky) {                                       \
            const int iq = oq + ky - 1;                                        \
            if (iq < 0 || iq > 15) continue;                                   \
            _Pragma("unroll")                                                  \
            for (int kx = 0; kx < 3; ++kx) {                                   \
                const int ik = ok + kx - 1;                                    \
                if (ik < 0 || ik > 15) continue;                               \
                const int pix = iq * 16 + ik;                                  \
                _Pragma("unroll")                                              \
                for (int s = 0; s < 16; ++s)                                   \
                    accv += lds_c[s * 260 + pix] * tw[((PASS)*16 + s)*9 + ky*3 + kx]; \
            }                                                                  \
        }                                                                      \
    } while (0)

    K1_LOAD(0, 0);
    #pragma unroll
    for (int it = 0; it < 8; ++it) {
        if (it < 7) {
            switch (it & 1) {
                case 0: K1_LOAD(1, it + 1); break;
                default: K1_LOAD(0, it + 1); break;
            }
        }
        switch (it & 1) {
            case 0: K1_COMP(0, it); break;
            default: K1_COMP(1, it); break;
        }
        if (it == 3) {
            __syncthreads();
            K1_CONV(0);
            __syncthreads();
        }
    }

    #pragma unroll
    for (int r = 0; r < 4; ++r)
        sl_part[wid][g * 4 + r][colb] = acc_sl[r];
    __syncthreads();
    K1_CONV(1);

    affRaw[(size_t)bid * T2 + tid] = accv;

    {
        const int t = tid >> 4, qq = tid & 15;
        const float s = sl_part[0][t][qq] + sl_part[1][t][qq] +
                        sl_part[2][t][qq] + sl_part[3][t][qq];
        SLout[((size_t)(b * TT + t) * NS + qq) * LL + l] = s * 0.03125f;
    }
#undef K1_LOAD
#undef K1_COMP
#undef K1_CONV
}

// ---------------------------------------------------------------------------
// Kernel 2 (MFMA): LayerNorm + MLP + residual via compensated bf16 MFMA.
// 49 blocks x 32 rows. A.B^T pattern verified by the SL path (R7, 3e-8):
// both fragments row-major by lane&15, 8 k-elems; C: row=(lane>>4)*4+reg,
// col=lane&15. Weights pre-split (kprep_w). buf reused: ln -> gelu(h).
// ---------------------------------------------------------------------------
__global__ __launch_bounds__(256) void k2_mfma(
        const float* __restrict__ affRaw,
        const float* __restrict__ lng, const float* __restrict__ lnb,
        const uint32_t* __restrict__ w1h, const uint32_t* __restrict__ w1l,
        const float* __restrict__ b1,
        const uint32_t* __restrict__ w2h, const uint32_t* __restrict__ w2l,
        const float* __restrict__ b2,
        float* __restrict__ affRes) {
    __shared__ __align__(16) float buf[32 * 260];
    const int tid = threadIdx.x, wid = tid >> 6, lane = tid & 63;
    const int colb = lane & 15, g = lane >> 4;
    const int row0 = blockIdx.x * 32;

    // LayerNorm: wave w handles rows w*8 .. w*8+7
    #pragma unroll
    for (int rr = 0; rr < 8; ++rr) {
        const int r = wid * 8 + rr;
        const float* xr = affRaw + (size_t)(row0 + r) * 256;
        const float4 x = reinterpret_cast<const float4*>(xr)[lane];
        float sm = x.x + x.y + x.z + x.w;
        float ss = x.x * x.x + x.y * x.y + x.z * x.z + x.w * x.w;
        #pragma unroll
        for (int m = 1; m < 64; m <<= 1) {
            sm += __shfl_xor(sm, m, 64);
            ss += __shfl_xor(ss, m, 64);
        }
        const float mean = sm * (1.f / 256.f);
        const float var = ss * (1.f / 256.f) - mean * mean;
        const float inv = rsqrtf(var + 1e-5f);
        const float4 g4 = reinterpret_cast<const float4*>(lng)[lane];
        const float4 bb = reinterpret_cast<const float4*>(lnb)[lane];
        float4 ln;
        ln.x = (x.x - mean) * inv * g4.x + bb.x;
        ln.y = (x.y - mean) * inv * g4.y + bb.y;
        ln.z = (x.z - mean) * inv * g4.z + bb.z;
        ln.w = (x.w - mean) * inv * g4.w + bb.w;
        *reinterpret_cast<float4*>(buf + r * 260 + lane * 4) = ln;
    }
    __syncthreads();

    // GEMM macro: acc[m][nn] += buf-rows . W^T  (compensated 3-term)
#define K2_GEMM(WH, WL, ACC) do {                                              \
        _Pragma("unroll")                                                      \
        for (int c = 0; c < 8; ++c) {                                          \
            bf16x8 a0h, a0l, a1h, a1l;                                         \
            {                                                                  \
                const float* ap0 = buf + (0*16 + colb) * 260 + c * 32 + g * 8; \
                const float* ap1 = buf + (1*16 + colb) * 260 + c * 32 + g * 8; \
                pksplit(*reinterpret_cast<const float4*>(ap0),                 \
                        *reinterpret_cast<const float4*>(ap0 + 4), a0h, a0l);  \
                pksplit(*reinterpret_cast<const float4*>(ap1),                 \
                        *reinterpret_cast<const float4*>(ap1 + 4), a1h, a1l);  \
            }                                                                  \
            _Pragma("unroll")                                                  \
            for (int nn = 0; nn < 4; ++nn) {                                   \
                const int jp = ((wid * 4 + nn) * 16 + colb) * 128 + c * 16 + g * 4; \
                const bf16x8 wh = __builtin_bit_cast(bf16x8,                   \
                    *reinterpret_cast<const uint4*>(WH + jp));                 \
                const bf16x8 wl = __builtin_bit_cast(bf16x8,                   \
                    *reinterpret_cast<const uint4*>(WL + jp));                 \
                ACC[0][nn] = __builtin_amdgcn_mfma_f32_16x16x32_bf16(a0h, wh, ACC[0][nn], 0, 0, 0); \
                ACC[0][nn] = __builtin_amdgcn_mfma_f32_16x16x32_bf16(a0h, wl, ACC[0][nn], 0, 0, 0); \
                ACC[0][nn] = __builtin_amdgcn_mfma_f32_16x16x32_bf16(a0l, wh, ACC[0][nn], 0, 0, 0); \
                ACC[1][nn] = __builtin_amdgcn_mfma_f32_16x16x32_bf16(a1h, wh, ACC[1][nn], 0, 0, 0); \
                ACC[1][nn] = __builtin_amdgcn_mfma_f32_16x16x32_bf16(a1h, wl, ACC[1][nn], 0, 0, 0); \
                ACC[1][nn] = __builtin_amdgcn_mfma_f32_16x16x32_bf16(a1l, wh, ACC[1][nn], 0, 0, 0); \
            }                                                                  \
        }                                                                      \
    } while (0)

    f32x4 acc1[2][4];
    #pragma unroll
    for (int m = 0; m < 2; ++m)
        #pragma unroll
        for (int nn = 0; nn < 4; ++nn) acc1[m][nn] = (f32x4){0.f, 0.f, 0.f, 0.f};
    K2_GEMM(w1h, w1l, acc1);

    __syncthreads();   // all GEMM1 reads of buf done
    // gelu(h + b1) -> buf  (C layout: row = m*16 + g*4 + r, col = wid*64+nn*16+colb)
    const float kInvSqrt2 = 0.70710678118654752f;
    #pragma unroll
    for (int m = 0; m < 2; ++m)
        #pragma unroll
        for (int nn = 0; nn < 4; ++nn) {
            const int col = wid * 64 + nn * 16 + colb;
            const float bj = b1[col];
            #pragma unroll
            for (int r = 0; r < 4; ++r) {
                const float h = acc1[m][nn][r] + bj;
                buf[(m * 16 + g * 4 + r) * 260 + col] =
                    0.5f * h * (1.f + erff(h * kInvSqrt2));
            }
        }
    __syncthreads();

    f32x4 acc2[2][4];
    #pragma unroll
    for (int m = 0; m < 2; ++m)
        #pragma unroll
        for (int nn = 0; nn < 4; ++nn) acc2[m][nn] = (f32x4){0.f, 0.f, 0.f, 0.f};
    K2_GEMM(w2h, w2l, acc2);

    // epilogue: residual + b2
    #pragma unroll
    for (int m = 0; m < 2; ++m)
        #pragma unroll
        for (int nn = 0; nn < 4; ++nn) {
            const int col = wid * 64 + nn * 16 + colb;
            const float b2j = b2[col];
            #pragma unroll
            for (int r = 0; r < 4; ++r) {
                const size_t idx = (size_t)(row0 + m * 16 + g * 4 + r) * 256 + col;
                affRes[idx] = affRaw[idx] + acc2[m][nn][r] + b2j;
            }
        }
#undef K2_GEMM
}

// ---------------------------------------------------------------------------
// Kernel 3a: patch-grid 3x3 conv, split 16-ch per block (128 blocks).
// ---------------------------------------------------------------------------
__global__ __launch_bounds__(256) void k3a_pconv(
        const float* __restrict__ affRes, const float* __restrict__ pw,
        float* __restrict__ part) {
    __shared__ __align__(16) float lpw[144];
    const int b = blockIdx.x >> 4, cc = blockIdx.x & 15;
    const int tid = threadIdx.x;
    if (tid < 144) {
        const int kk = tid / 16, c = tid & 15;
        lpw[kk * 16 + c] = pw[(size_t)(cc * 16 + c) * 9 + kk];
    }
    __syncthreads();
    if (tid < 196) {
        const int p1 = tid / 14, p2 = tid % 14;
        float s = 0.f;
        #pragma unroll
        for (int ky = 0; ky < 3; ++ky) {
            const int ip1 = p1 + ky - 1;
            if (ip1 < 0 || ip1 > 13) continue;
            #pragma unroll
            for (int kx = 0; kx < 3; ++kx) {
                const int ip2 = p2 + kx - 1;
                if (ip2 < 0 || ip2 > 13) continue;
                const float4* ar = reinterpret_cast<const float4*>(
                    affRes + (size_t)(b * LL + ip1 * 14 + ip2) * 256 + cc * 16);
                const float4* wr = reinterpret_cast<const float4*>(lpw + (ky * 3 + kx) * 16);
                #pragma unroll
                for (int c4 = 0; c4 < 4; ++c4) s += dot4(ar[c4], wr[c4]);
            }
        }
        part[(cc * 8 + b) * 196 + tid] = s;
    }
}

__global__ void k3b_yt(const float* __restrict__ part,
                       const float* __restrict__ pcb, float* __restrict__ out) {
    const int b = blockIdx.x, tid = threadIdx.x;
    if (tid < 196) {
        float s = pcb[0];
        #pragma unroll
        for (int cc = 0; cc < 16; ++cc) s += part[(cc * 8 + b) * 196 + tid];
        out[b * 196 + tid] = s;
    }
}

// ---------------------------------------------------------------------------
// Kernel 4bc (merged, R13/R16-validated): softmax+q-sum -> ws, then PV.
// ---------------------------------------------------------------------------
__global__ __launch_bounds__(256) void k4bc(
        const float* __restrict__ SL, const float* __restrict__ vin,
        float* __restrict__ PS) {
    __shared__ float lp[16 * 200];
    __shared__ float ws[196];
    const int t = blockIdx.x, b = blockIdx.y, z = blockIdx.z;
    const int tid = threadIdx.x;
    const int qq = tid >> 4, j = tid & 15;
    const float* row = SL + (size_t)((b * TT + t) * NS + qq) * LL;
    float v[13];
    float m = -1e30f;
    #pragma unroll
    for (int i = 0; i < 13; ++i) {
        const int l = j + i * 16;
        v[i] = (l < LL) ? row[l] : -1e30f;
        m = fmaxf(m, v[i]);
    }
    #pragma unroll
    for (int msk = 1; msk < 16; msk <<= 1) m = fmaxf(m, __shfl_xor(m, msk, 64));
    float s = 0.f;
    #pragma unroll
    for (int i = 0; i < 13; ++i) {
        const int l = j + i * 16;
        v[i] = (l < LL) ? __expf(v[i] - m) : 0.f;
        s += v[i];
    }
    #pragma unroll
    for (int msk = 1; msk < 16; msk <<= 1) s += __shfl_xor(s, msk, 64);
    const float inv = 1.f / s;
    #pragma unroll
    for (int i = 0; i < 13; ++i) {
        const int l = j + i * 16;
        if (l < LL) lp[qq * 200 + l] = v[i] * inv;
    }
    __syncthreads();
    if (tid < LL) {
        float w = 0.f;
        #pragma unroll
        for (int qi = 0; qi < 16; ++qi) w += lp[qi * 200 + tid];
        ws[tid] = w;
    }
    __syncthreads();
    const int bt = b * TT + t;
    float4 acc = make_float4(0.f, 0.f, 0.f, 0.f);
    const float* vb = vin + ((size_t)bt * LP1 + 1 + z * 98) * DM + tid * 4;
    const float* wz = ws + z * 98;
    #pragma unroll 4
    for (int l = 0; l < 98; ++l) {
        const float4 vv = *reinterpret_cast<const float4*>(vb + (size_t)l * DM);
        const float w = wz[l];
        acc.x += w * vv.x; acc.y += w * vv.y; acc.z += w * vv.z; acc.w += w * vv.w;
    }
    *reinterpret_cast<float4*>(PS + ((size_t)bt * 2 + z) * DM + tid * 4) = acc;
}

// Kernel 4d: y_s[b,w] = (1/256) * sum over 32 (t,z) partials
__global__ void k4d_ys(const float* __restrict__ PS, float* __restrict__ out) {
    const int i = blockIdx.x * 256 + threadIdx.x;   // 0..8191
    const int b = i >> 10, w = i & 1023;
    float s = 0.f;
    #pragma unroll
    for (int tz = 0; tz < 32; ++tz) s += PS[((size_t)b * 32 + tz) * DM + w];
    out[1568 + i] = s * (1.f / 256.f);
}

// ---------------------------------------------------------------------------
extern "C" void kernel_launch(void* const* d_in, const int* in_sizes, int n_in,
                              void* d_out, int out_size, void* d_ws, size_t ws_size,
                              hipStream_t stream) {
    const float* q    = (const float*)d_in[0];
    const float* k    = (const float*)d_in[1];
    const float* v    = (const float*)d_in[2];
    const float* syno = (const float*)d_in[3];
    const float* tw   = (const float*)d_in[4];
    const float* tbv  = (const float*)d_in[5];
    const float* lng  = (const float*)d_in[6];
    const float* lnb  = (const float*)d_in[7];
    const float* w1   = (const float*)d_in[8];
    const float* b1   = (const float*)d_in[9];
    const float* w2   = (const float*)d_in[10];
    const float* b2   = (const float*)d_in[11];
    const float* pw   = (const float*)d_in[12];
    const float* pcb  = (const float*)d_in[13];
    float* out = (float*)d_out;

    float* ws = (float*)d_ws;
    float* affRaw = ws;                 // 401408 floats
    float* affRes = ws + 401408;        // 401408
    float* SL     = ws + 802816;        // 401408
    float* part   = ws + 1204224;       // 16*8*196 = 25088
    uint32_t* synoHi = (uint32_t*)(ws + 1235584);   // 8192 u32
    uint32_t* synoLo = (uint32_t*)(ws + 1243776);   // 8192 u32
    uint32_t* w1h = (uint32_t*)(ws + 1251968);      // 32768 u32
    uint32_t* w1l = (uint32_t*)(ws + 1284736);      // 32768 u32
    uint32_t* w2h = (uint32_t*)(ws + 1317504);      // 32768 u32
    uint32_t* w2l = (uint32_t*)(ws + 1350272);      // 32768 u32 (end 1383040 fl)
    float* PS     = ws;                 // 262144, aliases affRaw (k4bc after k2)

    // prep: syno + weight pre-splits
    hipLaunchKernelGGL(kprep, dim3(32), dim3(256), 0, stream, syno, synoHi, synoLo);
    hipLaunchKernelGGL(kprep_w, dim3(128), dim3(256), 0, stream,
                       w1, w2, w1h, w1l, w2h, w2l);
    // temporal path + fused spatial logits
    hipLaunchKernelGGL(k1_temporal, dim3(BB * LL), dim3(256), 0, stream,
                       q, k, tw, tbv, synoHi, synoLo, affRaw, SL);
    hipLaunchKernelGGL(k2_mfma, dim3(49), dim3(256), 0, stream,
                       affRaw, lng, lnb, w1h, w1l, b1, w2h, w2l, b2, affRes);
    hipLaunchKernelGGL(k3a_pconv, dim3(128), dim3(256), 0, stream,
                       affRes, pw, part);
    hipLaunchKernelGGL(k3b_yt, dim3(8), dim3(256), 0, stream, part, pcb, out);
    // spatial path
    hipLaunchKernelGGL(k4bc, dim3(16, 8, 2), dim3(256), 0, stream, SL, v, PS);
    hipLaunchKernelGGL(k4d_ys, dim3(32), dim3(256), 0, stream, PS, out);
}

// Round 18
// 128.773 us; speedup vs baseline: 1.1358x; 1.0269x over previous
//
#include <hip/hip_runtime.h>
#include <hip/hip_bf16.h>
#include <math.h>

// Problem constants
#define BB 8
#define TT 16
#define PP 14
#define LL 196      // P*P
#define HH 16
#define DD 64
#define DM 1024     // H*D
#define NS 16
#define T2 256      // T*T
#define LP1 197

using bf16x8 = __attribute__((ext_vector_type(8))) short;
using f32x4  = __attribute__((ext_vector_type(4))) float;

__device__ __forceinline__ float dot4(float4 a, float4 b) {
    return a.x*b.x + a.y*b.y + a.z*b.z + a.w*b.w;
}

// round-to-nearest-even bf16 pack of two finite fp32
__device__ __forceinline__ uint32_t pkbf(float lo, float hi) {
    uint32_t a = __builtin_bit_cast(uint32_t, lo);
    uint32_t b = __builtin_bit_cast(uint32_t, hi);
    a += 0x7FFFu + ((a >> 16) & 1u);
    b += 0x7FFFu + ((b >> 16) & 1u);
    return (a >> 16) | (b & 0xFFFF0000u);
}

// split pair (x,y) into hi/lo bf16 words: x ~= hi.x + lo.x exactly to ~2^-18
__device__ __forceinline__ void split2(float x, float y, uint32_t* h, uint32_t* lo) {
    const uint32_t hh = pkbf(x, y);
    const float hx = __builtin_bit_cast(float, hh << 16);
    const float hy = __builtin_bit_cast(float, hh & 0xFFFF0000u);
    *h = hh;
    *lo = pkbf(x - hx, y - hy);
}

__device__ __forceinline__ void pksplit(float4 p, float4 q, bf16x8& hi, bf16x8& lo) {
    uint32_t uh[4], ul[4];
    split2(p.x, p.y, &uh[0], &ul[0]);
    split2(p.z, p.w, &uh[1], &ul[1]);
    split2(q.x, q.y, &uh[2], &ul[2]);
    split2(q.z, q.w, &uh[3], &ul[3]);
    struct U4 { uint32_t v[4]; } th, tl;
    th.v[0] = uh[0]; th.v[1] = uh[1]; th.v[2] = uh[2]; th.v[3] = uh[3];
    tl.v[0] = ul[0]; tl.v[1] = ul[1]; tl.v[2] = ul[2]; tl.v[3] = ul[3];
    hi = __builtin_bit_cast(bf16x8, th);
    lo = __builtin_bit_cast(bf16x8, tl);
}

// ---------------------------------------------------------------------------
// Kernel 0 (merged preps): blocks 0-31 pre-split syno; blocks 32-159 pre-split
// w1/w2 into hi/lo bf16 pair-words.
// ---------------------------------------------------------------------------
__global__ __launch_bounds__(256) void kprep_all(
        const float* __restrict__ syno,
        const float* __restrict__ w1, const float* __restrict__ w2,
        uint32_t* __restrict__ synoHi, uint32_t* __restrict__ synoLo,
        uint32_t* __restrict__ w1h, uint32_t* __restrict__ w1l,
        uint32_t* __restrict__ w2h, uint32_t* __restrict__ w2l) {
    const int bid = blockIdx.x, tid = threadIdx.x;
    if (bid < 32) {
        const int i = bid * 256 + tid;              // 0..8191
        uint32_t h, lo;
        split2(syno[2 * i], syno[2 * i + 1], &h, &lo);
        synoHi[i] = h;
        synoLo[i] = lo;
    } else {
        const int i = (bid - 32) * 256 + tid;       // 0..32767
        uint32_t h, lo;
        split2(w1[2 * i], w1[2 * i + 1], &h, &lo);
        w1h[i] = h; w1l[i] = lo;
        split2(w2[2 * i], w2[2 * i + 1], &h, &lo);
        w2h[i] = h; w2l[i] = lo;
    }
}

// ---------------------------------------------------------------------------
// Kernel 1 (v10, R14-best, frozen): depth-2 structure, two conv passes,
// no softmax max-pass (bounded logits). ~92us — pinned across 9 structural
// variants (chain-depth, coalescing, occupancy all exonerated).
// ---------------------------------------------------------------------------
__global__ __launch_bounds__(256) void k1_temporal(
        const float* __restrict__ qin, const float* __restrict__ kin,
        const float* __restrict__ tw,  const float* __restrict__ tbv,
        const uint32_t* __restrict__ synoHi, const uint32_t* __restrict__ synoLo,
        float* __restrict__ affRaw, float* __restrict__ SLout) {
    __shared__ __align__(16) float lds_c[16 * 260];   // [slot][pix]
    __shared__ __align__(16) float sl_part[4][16][16];

    const int bid = blockIdx.x, b = bid / LL, l = bid % LL;
    const int tid = threadIdx.x, wid = tid >> 6, lane = tid & 63;
    const int mrow = lane & 15;            // A-fragment row = frame
    const int g = lane >> 4;               // k-chunk group
    const int colb = lane & 15;
    const int oq = tid >> 4, ok = tid & 15;

    const size_t rowbase = ((size_t)(b*TT + mrow)*LP1 + 1 + l)*DM + g*8;
    f32x4 acc_sl = {0.f, 0.f, 0.f, 0.f};
    float accv = tbv[0];

    float4 A[2][4];
    uint4  S[2][4];

#define K1_LOAD(BUF, IT) do {                                                  \
        const int ch_ = 2*wid + 8*((IT) >> 1) + ((IT) & 1);                    \
        const float* sp_ = ((IT) < 4) ? qin : kin;                             \
        const float* base_ = sp_ + rowbase + (size_t)(ch_ & 15) * DD;          \
        A[BUF][0] = *reinterpret_cast<const float4*>(base_);                   \
        A[BUF][1] = *reinterpret_cast<const float4*>(base_ + 4);               \
        A[BUF][2] = *reinterpret_cast<const float4*>(base_ + 32);              \
        A[BUF][3] = *reinterpret_cast<const float4*>(base_ + 36);              \
        if ((IT) >= 4) {                                                       \
            const int off_ = colb * 512 + (ch_ - 16) * 32 + g * 4;             \
            S[BUF][0] = *reinterpret_cast<const uint4*>(synoHi + off_);        \
            S[BUF][1] = *reinterpret_cast<const uint4*>(synoLo + off_);        \
            S[BUF][2] = *reinterpret_cast<const uint4*>(synoHi + off_ + 16);   \
            S[BUF][3] = *reinterpret_cast<const uint4*>(synoLo + off_ + 16);   \
        }                                                                      \
    } while (0)

#define K1_COMP(BUF, IT) do {                                                  \
        bf16x8 h1, l1, h2, l2;                                                 \
        pksplit(A[BUF][0], A[BUF][1], h1, l1);                                 \
        pksplit(A[BUF][2], A[BUF][3], h2, l2);                                 \
        f32x4 acc = {0.f, 0.f, 0.f, 0.f};                                      \
        acc = __builtin_amdgcn_mfma_f32_16x16x32_bf16(h1, h1, acc, 0, 0, 0);   \
        acc = __builtin_amdgcn_mfma_f32_16x16x32_bf16(h1, l1, acc, 0, 0, 0);   \
        acc = __builtin_amdgcn_mfma_f32_16x16x32_bf16(l1, h1, acc, 0, 0, 0);   \
        acc = __builtin_amdgcn_mfma_f32_16x16x32_bf16(h2, h2, acc, 0, 0, 0);   \
        acc = __builtin_amdgcn_mfma_f32_16x16x32_bf16(h2, l2, acc, 0, 0, 0);   \
        acc = __builtin_amdgcn_mfma_f32_16x16x32_bf16(l2, h2, acc, 0, 0, 0);   \
        if ((IT) >= 4) {                                                       \
            const bf16x8 sh1 = __builtin_bit_cast(bf16x8, S[BUF][0]);          \
            const bf16x8 sl1 = __builtin_bit_cast(bf16x8, S[BUF][1]);          \
            const bf16x8 sh2 = __builtin_bit_cast(bf16x8, S[BUF][2]);          \
            const bf16x8 sl2 = __builtin_bit_cast(bf16x8, S[BUF][3]);          \
            acc_sl = __builtin_amdgcn_mfma_f32_16x16x32_bf16(h1, sh1, acc_sl, 0, 0, 0); \
            acc_sl = __builtin_amdgcn_mfma_f32_16x16x32_bf16(h1, sl1, acc_sl, 0, 0, 0); \
            acc_sl = __builtin_amdgcn_mfma_f32_16x16x32_bf16(l1, sh1, acc_sl, 0, 0, 0); \
            acc_sl = __builtin_amdgcn_mfma_f32_16x16x32_bf16(h2, sh2, acc_sl, 0, 0, 0); \
            acc_sl = __builtin_amdgcn_mfma_f32_16x16x32_bf16(h2, sl2, acc_sl, 0, 0, 0); \
            acc_sl = __builtin_amdgcn_mfma_f32_16x16x32_bf16(l2, sh2, acc_sl, 0, 0, 0); \
        }                                                                      \
        const float e0 = __expf(acc[0] * 0.125f);                              \
        const float e1 = __expf(acc[1] * 0.125f);                              \
        const float e2 = __expf(acc[2] * 0.125f);                              \
        const float e3 = __expf(acc[3] * 0.125f);                              \
        float s0 = e0, s1 = e1, s2 = e2, s3 = e3;                              \
        _Pragma("unroll")                                                      \
        for (int msk = 1; msk < 16; msk <<= 1) {                               \
            s0 += __shfl_xor(s0, msk, 64);                                     \
            s1 += __shfl_xor(s1, msk, 64);                                     \
            s2 += __shfl_xor(s2, msk, 64);                                     \
            s3 += __shfl_xor(s3, msk, 64);                                     \
        }                                                                      \
        const int slot_ = 2*wid + 8*(((IT) >> 1) & 1) + ((IT) & 1);            \
        float* cp_ = lds_c + slot_ * 260;                                      \
        cp_[(g*4 + 0)*16 + colb] = e0 / s0;                                    \
        cp_[(g*4 + 1)*16 + colb] = e1 / s1;                                    \
        cp_[(g*4 + 2)*16 + colb] = e2 / s2;                                    \
        cp_[(g*4 + 3)*16 + colb] = e3 / s3;                                    \
    } while (0)

#define K1_CONV(PASS) do {                                                     \
        _Pragma("unroll")                                                      \
        for (int ky = 0; ky < 3; ++ky) {                                       \
            const int iq = oq + ky - 1;                                        \
            if (iq < 0 || iq > 15) continue;                                   \
            _Pragma("unroll")                                                  \
            for (int kx = 0; kx < 3; ++kx) {                                   \
                const int ik = ok + kx - 1;                                    \
                if (ik < 0 || ik > 15) continue;                               \
                const int pix = iq * 16 + ik;                                  \
                _Pragma("unroll")                                              \
                for (int s = 0; s < 16; ++s)                                   \
                    accv += lds_c[s * 260 + pix] * tw[((PASS)*16 + s)*9 + ky*3 + kx]; \
            }                                                                  \
        }                                                                      \
    } while (0)

    K1_LOAD(0, 0);
    #pragma unroll
    for (int it = 0; it < 8; ++it) {
        if (it < 7) {
            switch (it & 1) {
                case 0: K1_LOAD(1, it + 1); break;
                default: K1_LOAD(0, it + 1); break;
            }
        }
        switch (it & 1) {
            case 0: K1_COMP(0, it); break;
            default: K1_COMP(1, it); break;
        }
        if (it == 3) {
            __syncthreads();
            K1_CONV(0);
            __syncthreads();
        }
    }

    #pragma unroll
    for (int r = 0; r < 4; ++r)
        sl_part[wid][g * 4 + r][colb] = acc_sl[r];
    __syncthreads();
    K1_CONV(1);

    affRaw[(size_t)bid * T2 + tid] = accv;

    {
        const int t = tid >> 4, qq = tid & 15;
        const float s = sl_part[0][t][qq] + sl_part[1][t][qq] +
                        sl_part[2][t][qq] + sl_part[3][t][qq];
        SLout[((size_t)(b * TT + t) * NS + qq) * LL + l] = s * 0.03125f;
    }
#undef K1_LOAD
#undef K1_COMP
#undef K1_CONV
}

// ---------------------------------------------------------------------------
// Kernel 2 (MFMA, R17-validated): LayerNorm + MLP + residual via compensated
// bf16 MFMA. 49 blocks x 32 rows.
// ---------------------------------------------------------------------------
__global__ __launch_bounds__(256) void k2_mfma(
        const float* __restrict__ affRaw,
        const float* __restrict__ lng, const float* __restrict__ lnb,
        const uint32_t* __restrict__ w1h, const uint32_t* __restrict__ w1l,
        const float* __restrict__ b1,
        const uint32_t* __restrict__ w2h, const uint32_t* __restrict__ w2l,
        const float* __restrict__ b2,
        float* __restrict__ affRes) {
    __shared__ __align__(16) float buf[32 * 260];
    const int tid = threadIdx.x, wid = tid >> 6, lane = tid & 63;
    const int colb = lane & 15, g = lane >> 4;
    const int row0 = blockIdx.x * 32;

    #pragma unroll
    for (int rr = 0; rr < 8; ++rr) {
        const int r = wid * 8 + rr;
        const float* xr = affRaw + (size_t)(row0 + r) * 256;
        const float4 x = reinterpret_cast<const float4*>(xr)[lane];
        float sm = x.x + x.y + x.z + x.w;
        float ss = x.x * x.x + x.y * x.y + x.z * x.z + x.w * x.w;
        #pragma unroll
        for (int m = 1; m < 64; m <<= 1) {
            sm += __shfl_xor(sm, m, 64);
            ss += __shfl_xor(ss, m, 64);
        }
        const float mean = sm * (1.f / 256.f);
        const float var = ss * (1.f / 256.f) - mean * mean;
        const float inv = rsqrtf(var + 1e-5f);
        const float4 g4 = reinterpret_cast<const float4*>(lng)[lane];
        const float4 bb = reinterpret_cast<const float4*>(lnb)[lane];
        float4 ln;
        ln.x = (x.x - mean) * inv * g4.x + bb.x;
        ln.y = (x.y - mean) * inv * g4.y + bb.y;
        ln.z = (x.z - mean) * inv * g4.z + bb.z;
        ln.w = (x.w - mean) * inv * g4.w + bb.w;
        *reinterpret_cast<float4*>(buf + r * 260 + lane * 4) = ln;
    }
    __syncthreads();

#define K2_GEMM(WH, WL, ACC) do {                                              \
        _Pragma("unroll")                                                      \
        for (int c = 0; c < 8; ++c) {                                          \
            bf16x8 a0h, a0l, a1h, a1l;                                         \
            {                                                                  \
                const float* ap0 = buf + (0*16 + colb) * 260 + c * 32 + g * 8; \
                const float* ap1 = buf + (1*16 + colb) * 260 + c * 32 + g * 8; \
                pksplit(*reinterpret_cast<const float4*>(ap0),                 \
                        *reinterpret_cast<const float4*>(ap0 + 4), a0h, a0l);  \
                pksplit(*reinterpret_cast<const float4*>(ap1),                 \
                        *reinterpret_cast<const float4*>(ap1 + 4), a1h, a1l);  \
            }                                                                  \
            _Pragma("unroll")                                                  \
            for (int nn = 0; nn < 4; ++nn) {                                   \
                const int jp = ((wid * 4 + nn) * 16 + colb) * 128 + c * 16 + g * 4; \
                const bf16x8 wh = __builtin_bit_cast(bf16x8,                   \
                    *reinterpret_cast<const uint4*>(WH + jp));                 \
                const bf16x8 wl = __builtin_bit_cast(bf16x8,                   \
                    *reinterpret_cast<const uint4*>(WL + jp));                 \
                ACC[0][nn] = __builtin_amdgcn_mfma_f32_16x16x32_bf16(a0h, wh, ACC[0][nn], 0, 0, 0); \
                ACC[0][nn] = __builtin_amdgcn_mfma_f32_16x16x32_bf16(a0h, wl, ACC[0][nn], 0, 0, 0); \
                ACC[0][nn] = __builtin_amdgcn_mfma_f32_16x16x32_bf16(a0l, wh, ACC[0][nn], 0, 0, 0); \
                ACC[1][nn] = __builtin_amdgcn_mfma_f32_16x16x32_bf16(a1h, wh, ACC[1][nn], 0, 0, 0); \
                ACC[1][nn] = __builtin_amdgcn_mfma_f32_16x16x32_bf16(a1h, wl, ACC[1][nn], 0, 0, 0); \
                ACC[1][nn] = __builtin_amdgcn_mfma_f32_16x16x32_bf16(a1l, wh, ACC[1][nn], 0, 0, 0); \
            }                                                                  \
        }                                                                      \
    } while (0)

    f32x4 acc1[2][4];
    #pragma unroll
    for (int m = 0; m < 2; ++m)
        #pragma unroll
        for (int nn = 0; nn < 4; ++nn) acc1[m][nn] = (f32x4){0.f, 0.f, 0.f, 0.f};
    K2_GEMM(w1h, w1l, acc1);

    __syncthreads();
    const float kInvSqrt2 = 0.70710678118654752f;
    #pragma unroll
    for (int m = 0; m < 2; ++m)
        #pragma unroll
        for (int nn = 0; nn < 4; ++nn) {
            const int col = wid * 64 + nn * 16 + colb;
            const float bj = b1[col];
            #pragma unroll
            for (int r = 0; r < 4; ++r) {
                const float h = acc1[m][nn][r] + bj;
                buf[(m * 16 + g * 4 + r) * 260 + col] =
                    0.5f * h * (1.f + erff(h * kInvSqrt2));
            }
        }
    __syncthreads();

    f32x4 acc2[2][4];
    #pragma unroll
    for (int m = 0; m < 2; ++m)
        #pragma unroll
        for (int nn = 0; nn < 4; ++nn) acc2[m][nn] = (f32x4){0.f, 0.f, 0.f, 0.f};
    K2_GEMM(w2h, w2l, acc2);

    #pragma unroll
    for (int m = 0; m < 2; ++m)
        #pragma unroll
        for (int nn = 0; nn < 4; ++nn) {
            const int col = wid * 64 + nn * 16 + colb;
            const float b2j = b2[col];
            #pragma unroll
            for (int r = 0; r < 4; ++r) {
                const size_t idx = (size_t)(row0 + m * 16 + g * 4 + r) * 256 + col;
                affRes[idx] = affRaw[idx] + acc2[m][nn][r] + b2j;
            }
        }
#undef K2_GEMM
}

// ---------------------------------------------------------------------------
// Kernel 3a: patch-grid 3x3 conv, split 16-ch per block (128 blocks).
// ---------------------------------------------------------------------------
__global__ __launch_bounds__(256) void k3a_pconv(
        const float* __restrict__ affRes, const float* __restrict__ pw,
        float* __restrict__ part) {
    __shared__ __align__(16) float lpw[144];
    const int b = blockIdx.x >> 4, cc = blockIdx.x & 15;
    const int tid = threadIdx.x;
    if (tid < 144) {
        const int kk = tid / 16, c = tid & 15;
        lpw[kk * 16 + c] = pw[(size_t)(cc * 16 + c) * 9 + kk];
    }
    __syncthreads();
    if (tid < 196) {
        const int p1 = tid / 14, p2 = tid % 14;
        float s = 0.f;
        #pragma unroll
        for (int ky = 0; ky < 3; ++ky) {
            const int ip1 = p1 + ky - 1;
            if (ip1 < 0 || ip1 > 13) continue;
            #pragma unroll
            for (int kx = 0; kx < 3; ++kx) {
                const int ip2 = p2 + kx - 1;
                if (ip2 < 0 || ip2 > 13) continue;
                const float4* ar = reinterpret_cast<const float4*>(
                    affRes + (size_t)(b * LL + ip1 * 14 + ip2) * 256 + cc * 16);
                const float4* wr = reinterpret_cast<const float4*>(lpw + (ky * 3 + kx) * 16);
                #pragma unroll
                for (int c4 = 0; c4 < 4; ++c4) s += dot4(ar[c4], wr[c4]);
            }
        }
        part[(cc * 8 + b) * 196 + tid] = s;
    }
}

// ---------------------------------------------------------------------------
// Kernel 4bc (merged, R13/R16-validated): softmax+q-sum -> ws, then PV.
// ---------------------------------------------------------------------------
__global__ __launch_bounds__(256) void k4bc(
        const float* __restrict__ SL, const float* __restrict__ vin,
        float* __restrict__ PS) {
    __shared__ float lp[16 * 200];
    __shared__ float ws[196];
    const int t = blockIdx.x, b = blockIdx.y, z = blockIdx.z;
    const int tid = threadIdx.x;
    const int qq = tid >> 4, j = tid & 15;
    const float* row = SL + (size_t)((b * TT + t) * NS + qq) * LL;
    float v[13];
    float m = -1e30f;
    #pragma unroll
    for (int i = 0; i < 13; ++i) {
        const int l = j + i * 16;
        v[i] = (l < LL) ? row[l] : -1e30f;
        m = fmaxf(m, v[i]);
    }
    #pragma unroll
    for (int msk = 1; msk < 16; msk <<= 1) m = fmaxf(m, __shfl_xor(m, msk, 64));
    float s = 0.f;
    #pragma unroll
    for (int i = 0; i < 13; ++i) {
        const int l = j + i * 16;
        v[i] = (l < LL) ? __expf(v[i] - m) : 0.f;
        s += v[i];
    }
    #pragma unroll
    for (int msk = 1; msk < 16; msk <<= 1) s += __shfl_xor(s, msk, 64);
    const float inv = 1.f / s;
    #pragma unroll
    for (int i = 0; i < 13; ++i) {
        const int l = j + i * 16;
        if (l < LL) lp[qq * 200 + l] = v[i] * inv;
    }
    __syncthreads();
    if (tid < LL) {
        float w = 0.f;
        #pragma unroll
        for (int qi = 0; qi < 16; ++qi) w += lp[qi * 200 + tid];
        ws[tid] = w;
    }
    __syncthreads();
    const int bt = b * TT + t;
    float4 acc = make_float4(0.f, 0.f, 0.f, 0.f);
    const float* vb = vin + ((size_t)bt * LP1 + 1 + z * 98) * DM + tid * 4;
    const float* wz = ws + z * 98;
    #pragma unroll 4
    for (int l = 0; l < 98; ++l) {
        const float4 vv = *reinterpret_cast<const float4*>(vb + (size_t)l * DM);
        const float w = wz[l];
        acc.x += w * vv.x; acc.y += w * vv.y; acc.z += w * vv.z; acc.w += w * vv.w;
    }
    *reinterpret_cast<float4*>(PS + ((size_t)bt * 2 + z) * DM + tid * 4) = acc;
}

// ---------------------------------------------------------------------------
// Kernel 3b4d (merged finals): all 32 blocks do y_s reduction; blocks 0-7
// additionally sum the conv partials into y_t. Disjoint outputs.
// ---------------------------------------------------------------------------
__global__ __launch_bounds__(256) void k3b4d(
        const float* __restrict__ part, const float* __restrict__ pcb,
        const float* __restrict__ PS, float* __restrict__ out) {
    const int bid = blockIdx.x, tid = threadIdx.x;
    const int i = bid * 256 + tid;      // 0..8191
    const int b = i >> 10, w = i & 1023;
    float s = 0.f;
    #pragma unroll
    for (int tz = 0; tz < 32; ++tz) s += PS[((size_t)b * 32 + tz) * DM + w];
    out[1568 + i] = s * (1.f / 256.f);
    if (bid < 8 && tid < 196) {
        float s2 = pcb[0];
        #pragma unroll
        for (int cc = 0; cc < 16; ++cc) s2 += part[(cc * 8 + bid) * 196 + tid];
        out[bid * 196 + tid] = s2;
    }
}

// ---------------------------------------------------------------------------
extern "C" void kernel_launch(void* const* d_in, const int* in_sizes, int n_in,
                              void* d_out, int out_size, void* d_ws, size_t ws_size,
                              hipStream_t stream) {
    const float* q    = (const float*)d_in[0];
    const float* k    = (const float*)d_in[1];
    const float* v    = (const float*)d_in[2];
    const float* syno = (const float*)d_in[3];
    const float* tw   = (const float*)d_in[4];
    const float* tbv  = (const float*)d_in[5];
    const float* lng  = (const float*)d_in[6];
    const float* lnb  = (const float*)d_in[7];
    const float* w1   = (const float*)d_in[8];
    const float* b1   = (const float*)d_in[9];
    const float* w2   = (const float*)d_in[10];
    const float* b2   = (const float*)d_in[11];
    const float* pw   = (const float*)d_in[12];
    const float* pcb  = (const float*)d_in[13];
    float* out = (float*)d_out;

    float* ws = (float*)d_ws;
    float* affRaw = ws;                 // 401408 floats
    float* affRes = ws + 401408;        // 401408
    float* SL     = ws + 802816;        // 401408
    float* part   = ws + 1204224;       // 16*8*196 = 25088
    uint32_t* synoHi = (uint32_t*)(ws + 1235584);   // 8192 u32
    uint32_t* synoLo = (uint32_t*)(ws + 1243776);   // 8192 u32
    uint32_t* w1h = (uint32_t*)(ws + 1251968);      // 32768 u32
    uint32_t* w1l = (uint32_t*)(ws + 1284736);      // 32768 u32
    uint32_t* w2h = (uint32_t*)(ws + 1317504);      // 32768 u32
    uint32_t* w2l = (uint32_t*)(ws + 1350272);      // 32768 u32 (end 1383040 fl)
    float* PS     = ws;                 // 262144, aliases affRaw (k4bc after k2)

    // prep: syno + weight pre-splits (merged)
    hipLaunchKernelGGL(kprep_all, dim3(160), dim3(256), 0, stream,
                       syno, w1, w2, synoHi, synoLo, w1h, w1l, w2h, w2l);
    // temporal path + fused spatial logits
    hipLaunchKernelGGL(k1_temporal, dim3(BB * LL), dim3(256), 0, stream,
                       q, k, tw, tbv, synoHi, synoLo, affRaw, SL);
    hipLaunchKernelGGL(k2_mfma, dim3(49), dim3(256), 0, stream,
                       affRaw, lng, lnb, w1h, w1l, b1, w2h, w2l, b2, affRes);
    hipLaunchKernelGGL(k3a_pconv, dim3(128), dim3(256), 0, stream,
                       affRes, pw, part);
    // spatial path
    hipLaunchKernelGGL(k4bc, dim3(16, 8, 2), dim3(256), 0, stream, SL, v, PS);
    // merged finals (y_t sum + y_s reduction)
    hipLaunchKernelGGL(k3b4d, dim3(32), dim3(256), 0, stream, part, pcb, PS, out);
}